// Round 1
// baseline (2513.257 us; speedup 1.0000x reference)
//
#include <hip/hip_runtime.h>
#include <math.h>

// ---------------- constants ----------------
constexpr int BB   = 64;
constexpr int N1   = 512;
constexpr int NPB  = 1024;            // nodes per batch graph (N1+N2)
constexpr int NN   = BB * NPB;        // 65536 total nodes
constexpr int EALL = 1048576;         // total edges (both communities)
constexpr int EC   = 524288;          // edges per community
constexpr int NH   = 128;
constexpr int NCAT = 384;
constexpr int KTOP = 256;             // K1 == K2
constexpr int NP   = BB * KTOP;       // 16384 pooled nodes per community

// ---------------- graph prep ----------------
__global__ void k_count(const int* __restrict__ dst, int n, int* cnt) {
    int i = blockIdx.x * blockDim.x + threadIdx.x;
    if (i < n) atomicAdd(&cnt[dst[i]], 1);
}

__global__ void k_dis(const int* __restrict__ cnt, float* __restrict__ dis, int n) {
    int i = blockIdx.x * blockDim.x + threadIdx.x;
    if (i < n) dis[i] = 1.0f / sqrtf((float)cnt[i] + 1.0f);
}

__global__ void k_blocksum(const int* __restrict__ cnt, int* __restrict__ bsum) {
    __shared__ int s[256];
    int i = blockIdx.x * 256 + threadIdx.x;
    s[threadIdx.x] = cnt[i];
    __syncthreads();
    for (int st = 128; st > 0; st >>= 1) {
        if (threadIdx.x < st) s[threadIdx.x] += s[threadIdx.x + st];
        __syncthreads();
    }
    if (threadIdx.x == 0) bsum[blockIdx.x] = s[0];
}

__global__ void k_scan_bsum(int* bsum) {
    __shared__ int s[256];
    int t = threadIdx.x;
    s[t] = bsum[t];
    __syncthreads();
    if (t == 0) {
        int acc = 0;
        for (int i = 0; i < 256; i++) { int v = s[i]; s[i] = acc; acc += v; }
    }
    __syncthreads();
    bsum[t] = s[t];
}

__global__ void k_scan_final(const int* __restrict__ cnt, const int* __restrict__ bsum,
                             int* __restrict__ rowstart) {
    __shared__ int s[256];
    int i = blockIdx.x * 256 + threadIdx.x;
    s[threadIdx.x] = cnt[i];
    __syncthreads();
    if (threadIdx.x == 0) {
        int acc = bsum[blockIdx.x];
        for (int j = 0; j < 256; j++) { int v = s[j]; s[j] = acc; acc += v; }
    }
    __syncthreads();
    rowstart[i] = s[threadIdx.x];
    if (i == NN - 1) rowstart[NN] = EALL;
}

__global__ void k_csr_scatter(const int* __restrict__ src, const int* __restrict__ dst, int n,
                              const int* __restrict__ rowstart, int* cursor, int* __restrict__ csrc) {
    int i = blockIdx.x * blockDim.x + threadIdx.x;
    if (i < n) {
        int d = dst[i];
        int p = atomicAdd(&cursor[d], 1);
        csrc[rowstart[d] + p] = src[i];
    }
}

// ---------------- GEMM: C[M x 128] = A[M x KDIM] @ W[KDIM x 128] ----------------
template <int KDIM>
__global__ void k_gemm128(const float* __restrict__ A, int lda,
                          const float* __restrict__ W,
                          float* __restrict__ C, int ldc, int M) {
    __shared__ float w[128][128];
    int col  = threadIdx.x & 127;
    int half = threadIdx.x >> 7;        // 0..1
    int row0 = blockIdx.x * 32;
    float acc[16];
#pragma unroll
    for (int r = 0; r < 16; r++) acc[r] = 0.f;
    for (int k0 = 0; k0 < KDIM; k0 += 128) {
        for (int idx = threadIdx.x; idx < 128 * 128; idx += 256)
            w[idx >> 7][idx & 127] = W[(size_t)(k0 + (idx >> 7)) * 128 + (idx & 127)];
        __syncthreads();
        for (int rr = 0; rr < 16; rr++) {
            int row = row0 + half * 16 + rr;
            const float* a = A + (size_t)row * lda + k0;
            float s = acc[rr];
#pragma unroll 8
            for (int k = 0; k < 128; k++) s = fmaf(a[k], w[k][col], s);
            acc[rr] = s;
        }
        __syncthreads();
    }
    for (int rr = 0; rr < 16; rr++) {
        int row = row0 + half * 16 + rr;
        if (row < M) C[(size_t)row * ldc + col] = acc[rr];
    }
}

// ---------------- full-graph GCN aggregation (CSR gather) ----------------
__global__ void k_aggregate(const float* __restrict__ xw, const float* __restrict__ dis,
                            const int* __restrict__ rowstart, const int* __restrict__ csrc,
                            const float* __restrict__ bias, float* __restrict__ XC, int colbase) {
    int node = blockIdx.x * 2 + (threadIdx.x >> 7);
    int f    = threadIdx.x & 127;
    float di = dis[node];
    float acc = xw[(size_t)node * 128 + f] * di * di;
    int e0 = rowstart[node], e1 = rowstart[node + 1];
    for (int e = e0; e < e1; e++) {
        int s = csrc[e];
        acc += xw[(size_t)s * 128 + f] * dis[s] * di;
    }
    acc += bias[f];
    XC[(size_t)node * 384 + colbase + f] = fmaxf(acc, 0.f);
}

// ---------------- attention pool stage 1 (communities, dim 384) ----------------
__global__ void k_mean12(const float* __restrict__ XC, float* __restrict__ mean) {
    int seg = blockIdx.x;               // 0..127
    int c   = threadIdx.x;              // 0..383
    int b   = seg & 63;
    int base = b * NPB + ((seg >= 64) ? 512 : 0);
    float s = 0.f;
    for (int i = 0; i < 512; i++) s += XC[(size_t)(base + i) * 384 + c];
    mean[seg * 384 + c] = s * (1.0f / 512.0f);
}

__global__ void k_c12(const float* __restrict__ mean, const float* __restrict__ Wg,
                      float* __restrict__ c12) {
    int seg = blockIdx.x; int c = threadIdx.x;
    float s = 0.f;
    for (int k = 0; k < 384; k++) s = fmaf(mean[seg * 384 + k], Wg[(size_t)k * 384 + c], s);
    c12[seg * 384 + c] = tanhf(s);
}

__global__ void k_alpha12(const float* __restrict__ XC, const float* __restrict__ c12,
                          float* __restrict__ alpha) {
    int node = blockIdx.x * 4 + (threadIdx.x >> 6);
    int lane = threadIdx.x & 63;
    int b = node >> 10; int loc = node & 1023;
    int seg = (loc < 512) ? b : (b + 64);
    const float* xr = XC + (size_t)node * 384;
    const float* cr = c12 + seg * 384;
    float s = 0.f;
    for (int k = lane; k < 384; k += 64) s += xr[k] * cr[k];
    for (int off = 32; off; off >>= 1) s += __shfl_down(s, off);
    if (lane == 0) alpha[node] = 1.f / (1.f + expf(-s));
}

__global__ void k_gp(const float* __restrict__ XC, const float* __restrict__ alpha,
                     float* __restrict__ gp) {
    int seg = blockIdx.x; int c = threadIdx.x;
    int b = seg & 63;
    int base = b * NPB + ((seg >= 64) ? 512 : 0);
    float s = 0.f;
    for (int i = 0; i < 512; i++) { int g = base + i; s += XC[(size_t)g * 384 + c] * alpha[g]; }
    gp[seg * 384 + c] = s;
}

__global__ void k_pv(const float* __restrict__ gp, const float* __restrict__ Wal,
                     const float* __restrict__ bal, float* __restrict__ pv) {
    int row = blockIdx.x;               // 0..63
    int c   = threadIdx.x;              // 0..767
    float s = bal[c];
    for (int k = 0; k < 768; k++) {
        float v = (k < 384) ? gp[row * 384 + k] : gp[(64 + row) * 384 + (k - 384)];
        s = fmaf(v, Wal[(size_t)k * 768 + c], s);
    }
    pv[row * 768 + c] = s;
}

__global__ void k_pnorm(const float* __restrict__ pv, float* __restrict__ pnorm) {
    int id = blockIdx.x;                // 0..127 : h = id>>6, b = id&63
    int lane = threadIdx.x;
    int h = id >> 6, b = id & 63;
    const float* p = pv + b * 768 + h * 384;
    float s = 0.f;
    for (int k = lane; k < 384; k += 64) s += p[k] * p[k];
    for (int off = 32; off; off >>= 1) s += __shfl_down(s, off);
    if (lane == 0) pnorm[id] = sqrtf(s);
}

// ---------------- CAG pool: scores + per-batch top-K ----------------
__global__ void k_score(const float* __restrict__ XC, const float* __restrict__ pv,
                        const float* __restrict__ pnorm, float* __restrict__ sc, int comm) {
    int nl = blockIdx.x * 4 + (threadIdx.x >> 6);    // 0..32767 community-local
    int lane = threadIdx.x & 63;
    int b = nl >> 9; int i = nl & 511;
    int g = b * NPB + comm * 512 + i;
    const float* xr = XC + (size_t)g * 384;
    const float* pr = pv + b * 768 + comm * 384;
    float s = 0.f;
    for (int k = lane; k < 384; k += 64) s += xr[k] * pr[k];
    for (int off = 32; off; off >>= 1) s += __shfl_down(s, off);
    if (lane == 0) sc[nl] = s / pnorm[comm * 64 + b];
}

__global__ void k_topk(const float* __restrict__ sc, int* __restrict__ sel, int* __restrict__ nmap) {
    __shared__ float sv[512];
    __shared__ int   si[512];
    int b = blockIdx.x;
    int t = threadIdx.x;                // 0..255
    sv[t] = sc[b * 512 + t];           si[t] = t;
    sv[t + 256] = sc[b * 512 + t + 256]; si[t + 256] = t + 256;
    __syncthreads();
    for (int k2 = 2; k2 <= 512; k2 <<= 1) {
        for (int j = k2 >> 1; j > 0; j >>= 1) {
            for (int i = t; i < 512; i += 256) {
                int l = i ^ j;
                if (l > i) {
                    bool desc = ((i & k2) == 0);
                    float a = sv[i], bb2 = sv[l];
                    bool sw = desc ? (a < bb2) : (a > bb2);
                    if (sw) {
                        sv[i] = bb2; sv[l] = a;
                        int tmp = si[i]; si[i] = si[l]; si[l] = tmp;
                    }
                }
            }
            __syncthreads();
        }
    }
    // top 256 (descending). Rank order doesn't affect final output (relabeling).
    sel[b * 256 + t] = si[t];
    nmap[b * 512 + si[t]] = b * 256 + t;
}

__global__ void k_gather(const float* __restrict__ XC, const float* __restrict__ sc,
                         const int* __restrict__ sel, float* __restrict__ P, int comm) {
    int n = blockIdx.x;                 // 0..16383
    int c = threadIdx.x;                // 0..383
    int b = n >> 8;
    int old = sel[n];                   // local 0..511
    int g = b * NPB + comm * 512 + old;
    float sg = 1.f / (1.f + expf(-sc[b * 512 + old]));
    P[(size_t)n * 384 + c] = XC[(size_t)g * 384 + c] * sg;
}

// ---------------- pooled-graph GCN ----------------
__global__ void k_pooled_cnt(const int* __restrict__ srcc, const int* __restrict__ dstc,
                             const int* __restrict__ nmap, int* cnt) {
    int e = blockIdx.x * blockDim.x + threadIdx.x;
    if (e < EC) {
        int r = nmap[srcc[e]], c = nmap[dstc[e]];
        if (r >= 0 && c >= 0) atomicAdd(&cnt[c], 1);
    }
}

__global__ void k_init_self(const float* __restrict__ xw, const float* __restrict__ disp,
                            float* __restrict__ out) {
    int i = blockIdx.x * blockDim.x + threadIdx.x;   // NP*128
    int node = i >> 7;
    float d = disp[node];
    out[i] = xw[i] * d * d;
}

__global__ void k_pooled_scatter(const int* __restrict__ srcc, const int* __restrict__ dstc,
                                 const int* __restrict__ nmap, const float* __restrict__ disp,
                                 const float* __restrict__ xw, float* __restrict__ out) {
    int tid = blockIdx.x * blockDim.x + threadIdx.x;
    int e = tid >> 5; int gidx = (tid & 31) * 4;
    if (e >= EC) return;
    int r = nmap[srcc[e]], c = nmap[dstc[e]];
    if (r < 0 || c < 0) return;
    float coef = disp[r] * disp[c];
    const float* xs = xw + (size_t)r * 128 + gidx;
    float* od = out + (size_t)c * 128 + gidx;
#pragma unroll
    for (int q = 0; q < 4; q++) atomicAdd(&od[q], xs[q] * coef);
}

__global__ void k_bias_relu(float* __restrict__ out, const float* __restrict__ bias, int n) {
    int i = blockIdx.x * blockDim.x + threadIdx.x;
    if (i < n) out[i] = fmaxf(out[i] + bias[i & 127], 0.f);
}

// ---------------- final attention pools (dim 128, 256 nodes/segment) ----------------
__global__ void k_meanf(const float* __restrict__ H, float* __restrict__ mean) {
    int b = blockIdx.x; int c = threadIdx.x;        // 128
    float s = 0.f;
    for (int i = 0; i < 256; i++) s += H[(size_t)(b * 256 + i) * 128 + c];
    mean[b * 128 + c] = s * (1.0f / 256.0f);
}

__global__ void k_cfin(const float* __restrict__ mean, const float* __restrict__ Wg,
                       float* __restrict__ cf) {
    int b = blockIdx.x; int c = threadIdx.x;
    float s = 0.f;
    for (int k = 0; k < 128; k++) s = fmaf(mean[b * 128 + k], Wg[k * 128 + c], s);
    cf[b * 128 + c] = tanhf(s);
}

__global__ void k_alphaf(const float* __restrict__ H, const float* __restrict__ cf,
                         float* __restrict__ al) {
    int node = blockIdx.x * 4 + (threadIdx.x >> 6);
    int lane = threadIdx.x & 63;
    int b = node >> 8;
    const float* h = H + (size_t)node * 128;
    const float* c = cf + b * 128;
    float s = 0.f;
    for (int k = lane; k < 128; k += 64) s += h[k] * c[k];
    for (int off = 32; off; off >>= 1) s += __shfl_down(s, off);
    if (lane == 0) al[node] = 1.f / (1.f + expf(-s));
}

__global__ void k_gfin(const float* __restrict__ H, const float* __restrict__ al,
                       float* __restrict__ g, int off) {
    int b = blockIdx.x; int c = threadIdx.x;        // 128
    float s = 0.f;
    for (int i = 0; i < 256; i++) { int n = b * 256 + i; s += H[(size_t)n * 128 + c] * al[n]; }
    g[b * 256 + off + c] = s;
}

// ---------------- MLP head ----------------
__global__ void k_mlp(const float* __restrict__ G,
                      const float* __restrict__ Wl1, const float* __restrict__ bl1,
                      const float* __restrict__ Wl2, const float* __restrict__ bl2,
                      const float* __restrict__ Wl3, const float* __restrict__ bl3,
                      float* __restrict__ out) {
    __shared__ float t1[128], t2[64];
    int b = blockIdx.x; int t = threadIdx.x;        // 128 threads
    float s = bl1[t];
    for (int k = 0; k < 256; k++) s = fmaf(G[b * 256 + k], Wl1[k * 128 + t], s);
    t1[t] = fmaxf(s, 0.f);
    __syncthreads();
    if (t < 64) {
        float s2 = bl2[t];
        for (int k = 0; k < 128; k++) s2 = fmaf(t1[k], Wl2[k * 64 + t], s2);
        t2[t] = fmaxf(s2, 0.f);
    }
    __syncthreads();
    if (t < 2) {
        float s3 = bl3[t];
        for (int k = 0; k < 64; k++) s3 = fmaf(t2[k], Wl3[k * 2 + t], s3);
        out[b * 2 + t] = s3;
    }
}

// ---------------- launch ----------------
extern "C" void kernel_launch(void* const* d_in, const int* in_sizes, int n_in,
                              void* d_out, int out_size, void* d_ws, size_t ws_size,
                              hipStream_t stream) {
    const float* x       = (const float*)d_in[0];
    const int*   src_all = (const int*)d_in[1];
    const int*   dst_all = (const int*)d_in[2];
    const int*   src_c1  = (const int*)d_in[3];
    const int*   dst_c1  = (const int*)d_in[4];
    const int*   src_c2  = (const int*)d_in[5];
    const int*   dst_c2  = (const int*)d_in[6];
    const float* W1 = (const float*)d_in[7];   const float* b1 = (const float*)d_in[8];
    const float* W2 = (const float*)d_in[9];   const float* b2 = (const float*)d_in[10];
    const float* W3 = (const float*)d_in[11];  const float* b3 = (const float*)d_in[12];
    const float* Wg_att = (const float*)d_in[13];
    const float* Wal = (const float*)d_in[14]; const float* bal = (const float*)d_in[15];
    const float* Wf  = (const float*)d_in[16]; const float* bf  = (const float*)d_in[17];
    const float* Wg_fin = (const float*)d_in[18];
    const float* Wl1 = (const float*)d_in[19]; const float* bl1 = (const float*)d_in[20];
    const float* Wl2 = (const float*)d_in[21]; const float* bl2 = (const float*)d_in[22];
    const float* Wl3 = (const float*)d_in[23]; const float* bl3 = (const float*)d_in[24];
    float* out = (float*)d_out;

    // ---- workspace layout (floats) ----
    float* f = (float*)d_ws;
    size_t o = 0;
    float* XC   = f + o; o += (size_t)NN * 384;     // 96 MB  concat features
    float* SCR  = f + o; o += (size_t)NN * 128;     // 32 MB  xw scratch; later P + XWP
    float* H1P  = f + o; o += (size_t)NP * 128;     // 8 MB
    float* H2P  = f + o; o += (size_t)NP * 128;     // 8 MB
    int* ROWSTART = (int*)(f + o); o += 65552;
    int* CSRC     = (int*)(f + o); o += EALL;       // 4 MB
    int* CNT      = (int*)(f + o); o += NN;
    int* BSUM     = (int*)(f + o); o += 256;
    float* DIS    = f + o; o += NN;
    float* MEAN12 = f + o; o += 128 * 384;
    float* C12    = f + o; o += 128 * 384;
    float* ALPHA  = f + o; o += NN;
    float* GP     = f + o; o += 128 * 384;
    float* PV     = f + o; o += 64 * 768;
    float* PNORM  = f + o; o += 128;
    float* SC1    = f + o; o += 32768;
    float* SC2    = f + o; o += 32768;
    int* SEL1     = (int*)(f + o); o += 16384;
    int* SEL2     = (int*)(f + o); o += 16384;
    int* NMAP1    = (int*)(f + o); o += 32768;
    int* NMAP2    = (int*)(f + o); o += 32768;
    int* CNTP     = (int*)(f + o); o += 16384;
    float* DISP1  = f + o; o += 16384;
    float* DISP2  = f + o; o += 16384;
    float* MEANF  = f + o; o += 64 * 128;
    float* CFIN   = f + o; o += 64 * 128;
    float* ALF    = f + o; o += 16384;
    float* G12    = f + o; o += 64 * 256;
    size_t needed_bytes = o * sizeof(float);
    if (ws_size < needed_bytes) return;   // fail loudly (output stays poisoned)

    float* P1  = SCR;                      // 16384*384
    float* XWP = SCR + (size_t)NP * 384;   // 16384*128   (exactly fills SCR)

    // ---- full-graph CSR + degrees ----
    hipMemsetAsync(CNT, 0, NN * sizeof(int), stream);
    k_count<<<EALL / 256, 256, 0, stream>>>(dst_all, EALL, CNT);
    k_dis<<<NN / 256, 256, 0, stream>>>(CNT, DIS, NN);
    k_blocksum<<<256, 256, 0, stream>>>(CNT, BSUM);
    k_scan_bsum<<<1, 256, 0, stream>>>(BSUM);
    k_scan_final<<<256, 256, 0, stream>>>(CNT, BSUM, ROWSTART);
    hipMemsetAsync(CNT, 0, NN * sizeof(int), stream);   // reuse as cursor
    k_csr_scatter<<<EALL / 256, 256, 0, stream>>>(src_all, dst_all, EALL, ROWSTART, CNT, CSRC);

    // ---- 3 GCN layers into XC columns ----
    k_gemm128<128><<<NN / 32, 256, 0, stream>>>(x, 128, W1, SCR, 128, NN);
    k_aggregate<<<NN / 2, 256, 0, stream>>>(SCR, DIS, ROWSTART, CSRC, b1, XC, 0);
    k_gemm128<128><<<NN / 32, 256, 0, stream>>>(XC + 0, 384, W2, SCR, 128, NN);
    k_aggregate<<<NN / 2, 256, 0, stream>>>(SCR, DIS, ROWSTART, CSRC, b2, XC, 128);
    k_gemm128<128><<<NN / 32, 256, 0, stream>>>(XC + 128, 384, W3, SCR, 128, NN);
    k_aggregate<<<NN / 2, 256, 0, stream>>>(SCR, DIS, ROWSTART, CSRC, b3, XC, 256);

    // ---- attention pool over communities ----
    k_mean12<<<128, 384, 0, stream>>>(XC, MEAN12);
    k_c12<<<128, 384, 0, stream>>>(MEAN12, Wg_att, C12);
    k_alpha12<<<NN / 4, 256, 0, stream>>>(XC, C12, ALPHA);
    k_gp<<<128, 384, 0, stream>>>(XC, ALPHA, GP);
    k_pv<<<64, 768, 0, stream>>>(GP, Wal, bal, PV);
    k_pnorm<<<128, 64, 0, stream>>>(PV, PNORM);

    // ---- scores + top-K per batch ----
    k_score<<<32768 / 4, 256, 0, stream>>>(XC, PV, PNORM, SC1, 0);
    k_score<<<32768 / 4, 256, 0, stream>>>(XC, PV, PNORM, SC2, 1);
    hipMemsetAsync(NMAP1, 0xFF, 32768 * sizeof(int), stream);
    hipMemsetAsync(NMAP2, 0xFF, 32768 * sizeof(int), stream);
    k_topk<<<64, 256, 0, stream>>>(SC1, SEL1, NMAP1);
    k_topk<<<64, 256, 0, stream>>>(SC2, SEL2, NMAP2);

    // ---- pooled GCN, community 1 ----
    k_gather<<<NP, 384, 0, stream>>>(XC, SC1, SEL1, P1, 0);
    hipMemsetAsync(CNTP, 0, NP * sizeof(int), stream);
    k_pooled_cnt<<<EC / 256, 256, 0, stream>>>(src_c1, dst_c1, NMAP1, CNTP);
    k_dis<<<NP / 256, 256, 0, stream>>>(CNTP, DISP1, NP);
    k_gemm128<384><<<NP / 32, 256, 0, stream>>>(P1, 384, Wf, XWP, 128, NP);
    k_init_self<<<NP * 128 / 256, 256, 0, stream>>>(XWP, DISP1, H1P);
    k_pooled_scatter<<<EC * 32 / 256, 256, 0, stream>>>(src_c1, dst_c1, NMAP1, DISP1, XWP, H1P);
    k_bias_relu<<<NP * 128 / 256, 256, 0, stream>>>(H1P, bf, NP * 128);

    // ---- pooled GCN, community 2 (reuses SCR) ----
    k_gather<<<NP, 384, 0, stream>>>(XC, SC2, SEL2, P1, 1);
    hipMemsetAsync(CNTP, 0, NP * sizeof(int), stream);
    k_pooled_cnt<<<EC / 256, 256, 0, stream>>>(src_c2, dst_c2, NMAP2, CNTP);
    k_dis<<<NP / 256, 256, 0, stream>>>(CNTP, DISP2, NP);
    k_gemm128<384><<<NP / 32, 256, 0, stream>>>(P1, 384, Wf, XWP, 128, NP);
    k_init_self<<<NP * 128 / 256, 256, 0, stream>>>(XWP, DISP2, H2P);
    k_pooled_scatter<<<EC * 32 / 256, 256, 0, stream>>>(src_c2, dst_c2, NMAP2, DISP2, XWP, H2P);
    k_bias_relu<<<NP * 128 / 256, 256, 0, stream>>>(H2P, bf, NP * 128);

    // ---- final attention pools ----
    k_meanf<<<64, 128, 0, stream>>>(H1P, MEANF);
    k_cfin<<<64, 128, 0, stream>>>(MEANF, Wg_fin, CFIN);
    k_alphaf<<<NP / 4, 256, 0, stream>>>(H1P, CFIN, ALF);
    k_gfin<<<64, 128, 0, stream>>>(H1P, ALF, G12, 0);

    k_meanf<<<64, 128, 0, stream>>>(H2P, MEANF);
    k_cfin<<<64, 128, 0, stream>>>(MEANF, Wg_fin, CFIN);
    k_alphaf<<<NP / 4, 256, 0, stream>>>(H2P, CFIN, ALF);
    k_gfin<<<64, 128, 0, stream>>>(H2P, ALF, G12, 128);

    // ---- MLP head ----
    k_mlp<<<64, 128, 0, stream>>>(G12, Wl1, bl1, Wl2, bl2, Wl3, bl3, out);
}

// Round 2
// 1034.664 us; speedup vs baseline: 2.4291x; 2.4291x over previous
//
#include <hip/hip_runtime.h>
#include <math.h>

// ---------------- constants ----------------
constexpr int BB   = 64;
constexpr int NPB  = 1024;            // nodes per batch graph (N1+N2)
constexpr int NN   = BB * NPB;        // 65536 total nodes
constexpr int EALL = 1048576;         // total edges (both communities)
constexpr int EC   = 524288;          // edges per community
constexpr int KTOP = 256;             // K1 == K2
constexpr int NP   = BB * KTOP;       // 16384 pooled nodes per community

// ---------------- graph prep ----------------
__global__ void k_count(const int* __restrict__ dst, int n, int* cnt) {
    int i = blockIdx.x * blockDim.x + threadIdx.x;
    if (i < n) atomicAdd(&cnt[dst[i]], 1);
}

__global__ void k_dis(const int* __restrict__ cnt, float* __restrict__ dis, int n) {
    int i = blockIdx.x * blockDim.x + threadIdx.x;
    if (i < n) dis[i] = 1.0f / sqrtf((float)cnt[i] + 1.0f);
}

__global__ void k_blocksum(const int* __restrict__ cnt, int* __restrict__ bsum) {
    __shared__ int s[256];
    int i = blockIdx.x * 256 + threadIdx.x;
    s[threadIdx.x] = cnt[i];
    __syncthreads();
    for (int st = 128; st > 0; st >>= 1) {
        if (threadIdx.x < st) s[threadIdx.x] += s[threadIdx.x + st];
        __syncthreads();
    }
    if (threadIdx.x == 0) bsum[blockIdx.x] = s[0];
}

__global__ void k_scan_bsum(int* bsum, int g) {
    __shared__ int s[256];
    int t = threadIdx.x;
    s[t] = (t < g) ? bsum[t] : 0;
    __syncthreads();
    if (t == 0) {
        int acc = 0;
        for (int i = 0; i < g; i++) { int v = s[i]; s[i] = acc; acc += v; }
    }
    __syncthreads();
    if (t < g) bsum[t] = s[t];
}

__global__ void k_scan_final(const int* __restrict__ cnt, const int* __restrict__ bsum,
                             int* __restrict__ rowstart, int ntot) {
    __shared__ int s[256];
    int i = blockIdx.x * 256 + threadIdx.x;
    int myc = cnt[i];
    s[threadIdx.x] = myc;
    __syncthreads();
    if (threadIdx.x == 0) {
        int acc = bsum[blockIdx.x];
        for (int j = 0; j < 256; j++) { int v = s[j]; s[j] = acc; acc += v; }
    }
    __syncthreads();
    rowstart[i] = s[threadIdx.x];
    if (i == ntot - 1) rowstart[ntot] = s[threadIdx.x] + myc;
}

__global__ void k_csr_scatter(const int* __restrict__ src, const int* __restrict__ dst, int n,
                              const int* __restrict__ rowstart, int* cursor, int* __restrict__ csrc) {
    int i = blockIdx.x * blockDim.x + threadIdx.x;
    if (i < n) {
        int d = dst[i];
        int p = atomicAdd(&cursor[d], 1);
        csrc[rowstart[d] + p] = src[i];
    }
}

__global__ void k_csr_scatter_pooled(const int* __restrict__ src, const int* __restrict__ dst,
                                     const int* __restrict__ nmap, const int* __restrict__ rowstart,
                                     int* cursor, int* __restrict__ csre) {
    int e = blockIdx.x * blockDim.x + threadIdx.x;
    if (e < EC) {
        int r = nmap[src[e]], c = nmap[dst[e]];
        if (r >= 0 && c >= 0) {
            int p = atomicAdd(&cursor[c], 1);
            csre[rowstart[c] + p] = r;
        }
    }
}

// ---------------- GEMM: C[M x 128] = A[M x KDIM] @ W[KDIM x 128] ----------------
// 128x128 block tile, 8x8 per-thread micro-tile, A staged transposed in LDS.
template <int KDIM>
__global__ __launch_bounds__(256) void k_gemm_tile(const float* __restrict__ A, int lda,
                                                   const float* __restrict__ W,
                                                   float* __restrict__ C, int M) {
    __shared__ float As[32][136];      // [k][row], stride 136 -> 2-way bank alias only (free)
    __shared__ float Ws[32 * 128];     // [k][col] flat
    const int tid  = threadIdx.x;
    const int colg = tid & 15;         // c0 = colg*8
    const int rowg = tid >> 4;         // r0 = rowg*8
    const int c0 = colg * 8;
    const int r0 = rowg * 8;
    const int row0 = blockIdx.x * 128;

    const int arow = tid >> 1;         // 0..127
    const int aq   = tid & 1;

    float acc[8][8];
#pragma unroll
    for (int i = 0; i < 8; i++)
#pragma unroll
        for (int j = 0; j < 8; j++) acc[i][j] = 0.f;

    for (int k0 = 0; k0 < KDIM; k0 += 32) {
        __syncthreads();
        // stage A tile (128 rows x 32 k), transposed
        const float* Ap = A + (size_t)(row0 + arow) * lda + k0;
#pragma unroll
        for (int qq = 0; qq < 4; qq++) {
            int kk = (aq + 2 * qq) * 4;
            float4 av = *(const float4*)(Ap + kk);
            As[kk + 0][arow] = av.x;
            As[kk + 1][arow] = av.y;
            As[kk + 2][arow] = av.z;
            As[kk + 3][arow] = av.w;
        }
        // stage W tile (32 x 128)
#pragma unroll
        for (int q = 0; q < 4; q++) {
            int f = tid + 256 * q;
            float4 wv = *(const float4*)(W + (size_t)k0 * 128 + f * 4);
            *(float4*)&Ws[f * 4] = wv;
        }
        __syncthreads();
#pragma unroll 2
        for (int kk = 0; kk < 32; kk++) {
            float4 a0 = *(const float4*)&As[kk][r0];
            float4 a1 = *(const float4*)&As[kk][r0 + 4];
            float4 b0 = *(const float4*)&Ws[kk * 128 + c0];
            float4 b1 = *(const float4*)&Ws[kk * 128 + c0 + 4];
            float a[8] = {a0.x, a0.y, a0.z, a0.w, a1.x, a1.y, a1.z, a1.w};
            float b[8] = {b0.x, b0.y, b0.z, b0.w, b1.x, b1.y, b1.z, b1.w};
#pragma unroll
            for (int i = 0; i < 8; i++)
#pragma unroll
                for (int j = 0; j < 8; j++)
                    acc[i][j] = fmaf(a[i], b[j], acc[i][j]);
        }
    }
#pragma unroll
    for (int i = 0; i < 8; i++) {
        int row = row0 + r0 + i;
        if (row < M) {
            float4 o0 = {acc[i][0], acc[i][1], acc[i][2], acc[i][3]};
            float4 o1 = {acc[i][4], acc[i][5], acc[i][6], acc[i][7]};
            *(float4*)(C + (size_t)row * 128 + c0) = o0;
            *(float4*)(C + (size_t)row * 128 + c0 + 4) = o1;
        }
    }
}

// ---------------- full-graph GCN aggregation (CSR gather, float4) ----------------
__global__ void k_aggregate4(const float* __restrict__ xw, const float* __restrict__ dis,
                             const int* __restrict__ rowstart, const int* __restrict__ csrc,
                             const float* __restrict__ bias, float* __restrict__ XC, int colbase) {
    int node = blockIdx.x * 8 + (threadIdx.x >> 5);
    int l    = threadIdx.x & 31;
    const float4* xw4 = (const float4*)xw;
    float di = dis[node];
    float4 v = xw4[(size_t)node * 32 + l];
    float4 acc;
    float dd = di * di;
    acc.x = v.x * dd; acc.y = v.y * dd; acc.z = v.z * dd; acc.w = v.w * dd;
    int e0 = rowstart[node], e1 = rowstart[node + 1];
    for (int e = e0; e < e1; e++) {
        int s = csrc[e];
        float w = dis[s] * di;
        float4 u = xw4[(size_t)s * 32 + l];
        acc.x += u.x * w; acc.y += u.y * w; acc.z += u.z * w; acc.w += u.w * w;
    }
    float4 b4 = ((const float4*)bias)[l];
    acc.x = fmaxf(acc.x + b4.x, 0.f);
    acc.y = fmaxf(acc.y + b4.y, 0.f);
    acc.z = fmaxf(acc.z + b4.z, 0.f);
    acc.w = fmaxf(acc.w + b4.w, 0.f);
    *(float4*)(XC + (size_t)node * 384 + colbase + l * 4) = acc;
}

// pooled variant: output stride 128, bias+relu fused
__global__ void k_aggregate_pooled(const float* __restrict__ xw, const float* __restrict__ disp,
                                   const int* __restrict__ rowstart, const int* __restrict__ csre,
                                   const float* __restrict__ bias, float* __restrict__ H) {
    int node = blockIdx.x * 8 + (threadIdx.x >> 5);
    int l    = threadIdx.x & 31;
    const float4* xw4 = (const float4*)xw;
    float di = disp[node];
    float4 v = xw4[(size_t)node * 32 + l];
    float4 acc;
    float dd = di * di;
    acc.x = v.x * dd; acc.y = v.y * dd; acc.z = v.z * dd; acc.w = v.w * dd;
    int e0 = rowstart[node], e1 = rowstart[node + 1];
    for (int e = e0; e < e1; e++) {
        int r = csre[e];
        float w = disp[r] * di;
        float4 u = xw4[(size_t)r * 32 + l];
        acc.x += u.x * w; acc.y += u.y * w; acc.z += u.z * w; acc.w += u.w * w;
    }
    float4 b4 = ((const float4*)bias)[l];
    acc.x = fmaxf(acc.x + b4.x, 0.f);
    acc.y = fmaxf(acc.y + b4.y, 0.f);
    acc.z = fmaxf(acc.z + b4.z, 0.f);
    acc.w = fmaxf(acc.w + b4.w, 0.f);
    *(float4*)(H + (size_t)node * 128 + l * 4) = acc;
}

// ---------------- attention pool stage 1 (communities, dim 384) ----------------
__global__ void k_mean12(const float* __restrict__ XC, float* __restrict__ mean) {
    int seg = blockIdx.x;               // 0..127
    int c   = threadIdx.x;              // 0..383
    int b   = seg & 63;
    int base = b * NPB + ((seg >= 64) ? 512 : 0);
    float s = 0.f;
    for (int i = 0; i < 512; i++) s += XC[(size_t)(base + i) * 384 + c];
    mean[seg * 384 + c] = s * (1.0f / 512.0f);
}

__global__ void k_c12(const float* __restrict__ mean, const float* __restrict__ Wg,
                      float* __restrict__ c12) {
    int seg = blockIdx.x; int c = threadIdx.x;
    float s = 0.f;
    for (int k = 0; k < 384; k++) s = fmaf(mean[seg * 384 + k], Wg[(size_t)k * 384 + c], s);
    c12[seg * 384 + c] = tanhf(s);
}

__global__ void k_alpha12(const float* __restrict__ XC, const float* __restrict__ c12,
                          float* __restrict__ alpha) {
    int node = blockIdx.x * 4 + (threadIdx.x >> 6);
    int lane = threadIdx.x & 63;
    int b = node >> 10; int loc = node & 1023;
    int seg = (loc < 512) ? b : (b + 64);
    const float* xr = XC + (size_t)node * 384;
    const float* cr = c12 + seg * 384;
    float s = 0.f;
    for (int k = lane; k < 384; k += 64) s += xr[k] * cr[k];
    for (int off = 32; off; off >>= 1) s += __shfl_down(s, off);
    if (lane == 0) alpha[node] = 1.f / (1.f + expf(-s));
}

__global__ void k_gp(const float* __restrict__ XC, const float* __restrict__ alpha,
                     float* __restrict__ gp) {
    int seg = blockIdx.x; int c = threadIdx.x;
    int b = seg & 63;
    int base = b * NPB + ((seg >= 64) ? 512 : 0);
    float s = 0.f;
    for (int i = 0; i < 512; i++) { int g = base + i; s += XC[(size_t)g * 384 + c] * alpha[g]; }
    gp[seg * 384 + c] = s;
}

__global__ void k_pv(const float* __restrict__ gp, const float* __restrict__ Wal,
                     const float* __restrict__ bal, float* __restrict__ pv) {
    int row = blockIdx.x;               // 0..63
    int c   = threadIdx.x;              // 0..767
    float s = bal[c];
    for (int k = 0; k < 768; k++) {
        float v = (k < 384) ? gp[row * 384 + k] : gp[(64 + row) * 384 + (k - 384)];
        s = fmaf(v, Wal[(size_t)k * 768 + c], s);
    }
    pv[row * 768 + c] = s;
}

__global__ void k_pnorm(const float* __restrict__ pv, float* __restrict__ pnorm) {
    int id = blockIdx.x;                // 0..127 : h = id>>6, b = id&63
    int lane = threadIdx.x;
    int h = id >> 6, b = id & 63;
    const float* p = pv + b * 768 + h * 384;
    float s = 0.f;
    for (int k = lane; k < 384; k += 64) s += p[k] * p[k];
    for (int off = 32; off; off >>= 1) s += __shfl_down(s, off);
    if (lane == 0) pnorm[id] = sqrtf(s);
}

// ---------------- CAG pool: scores + per-batch top-K ----------------
__global__ void k_score(const float* __restrict__ XC, const float* __restrict__ pv,
                        const float* __restrict__ pnorm, float* __restrict__ sc, int comm) {
    int nl = blockIdx.x * 4 + (threadIdx.x >> 6);    // community-local node
    int lane = threadIdx.x & 63;
    int b = nl >> 9; int i = nl & 511;
    int g = b * NPB + comm * 512 + i;
    const float* xr = XC + (size_t)g * 384;
    const float* pr = pv + b * 768 + comm * 384;
    float s = 0.f;
    for (int k = lane; k < 384; k += 64) s += xr[k] * pr[k];
    for (int off = 32; off; off >>= 1) s += __shfl_down(s, off);
    if (lane == 0) sc[nl] = s / pnorm[comm * 64 + b];
}

__global__ void k_topk(const float* __restrict__ sc, int* __restrict__ sel, int* __restrict__ nmap) {
    __shared__ float sv[512];
    __shared__ int   si[512];
    int b = blockIdx.x;
    int t = threadIdx.x;                // 0..255
    sv[t] = sc[b * 512 + t];             si[t] = t;
    sv[t + 256] = sc[b * 512 + t + 256]; si[t + 256] = t + 256;
    __syncthreads();
    for (int k2 = 2; k2 <= 512; k2 <<= 1) {
        for (int j = k2 >> 1; j > 0; j >>= 1) {
            for (int i = t; i < 512; i += 256) {
                int l = i ^ j;
                if (l > i) {
                    bool desc = ((i & k2) == 0);
                    float a = sv[i], bb2 = sv[l];
                    bool sw = desc ? (a < bb2) : (a > bb2);
                    if (sw) {
                        sv[i] = bb2; sv[l] = a;
                        int tmp = si[i]; si[i] = si[l]; si[l] = tmp;
                    }
                }
            }
            __syncthreads();
        }
    }
    sel[b * 256 + t] = si[t];
    nmap[b * 512 + si[t]] = b * 256 + t;        // rank id for selected
    nmap[b * 512 + si[t + 256]] = -1;           // not selected
}

__global__ void k_gather(const float* __restrict__ XC, const float* __restrict__ sc,
                         const int* __restrict__ sel, float* __restrict__ P, int comm) {
    int n = blockIdx.x;                 // 0..16383
    int c = threadIdx.x;                // 0..383
    int b = n >> 8;
    int old = sel[n];
    int g = b * NPB + comm * 512 + old;
    float sg = 1.f / (1.f + expf(-sc[b * 512 + old]));
    P[(size_t)n * 384 + c] = XC[(size_t)g * 384 + c] * sg;
}

__global__ void k_pooled_cnt(const int* __restrict__ srcc, const int* __restrict__ dstc,
                             const int* __restrict__ nmap, int* cnt) {
    int e = blockIdx.x * blockDim.x + threadIdx.x;
    if (e < EC) {
        int r = nmap[srcc[e]], c = nmap[dstc[e]];
        if (r >= 0 && c >= 0) atomicAdd(&cnt[c], 1);
    }
}

// ---------------- final attention pools (dim 128, 256 nodes/segment) ----------------
__global__ void k_meanf(const float* __restrict__ H, float* __restrict__ mean) {
    int b = blockIdx.x; int c = threadIdx.x;        // 128
    float s = 0.f;
    for (int i = 0; i < 256; i++) s += H[(size_t)(b * 256 + i) * 128 + c];
    mean[b * 128 + c] = s * (1.0f / 256.0f);
}

__global__ void k_cfin(const float* __restrict__ mean, const float* __restrict__ Wg,
                       float* __restrict__ cf) {
    int b = blockIdx.x; int c = threadIdx.x;
    float s = 0.f;
    for (int k = 0; k < 128; k++) s = fmaf(mean[b * 128 + k], Wg[k * 128 + c], s);
    cf[b * 128 + c] = tanhf(s);
}

__global__ void k_alphaf(const float* __restrict__ H, const float* __restrict__ cf,
                         float* __restrict__ al) {
    int node = blockIdx.x * 4 + (threadIdx.x >> 6);
    int lane = threadIdx.x & 63;
    int b = node >> 8;
    const float* h = H + (size_t)node * 128;
    const float* c = cf + b * 128;
    float s = 0.f;
    for (int k = lane; k < 128; k += 64) s += h[k] * c[k];
    for (int off = 32; off; off >>= 1) s += __shfl_down(s, off);
    if (lane == 0) al[node] = 1.f / (1.f + expf(-s));
}

__global__ void k_gfin(const float* __restrict__ H, const float* __restrict__ al,
                       float* __restrict__ g, int off) {
    int b = blockIdx.x; int c = threadIdx.x;        // 128
    float s = 0.f;
    for (int i = 0; i < 256; i++) { int n = b * 256 + i; s += H[(size_t)n * 128 + c] * al[n]; }
    g[b * 256 + off + c] = s;
}

// ---------------- MLP head ----------------
__global__ void k_mlp(const float* __restrict__ G,
                      const float* __restrict__ Wl1, const float* __restrict__ bl1,
                      const float* __restrict__ Wl2, const float* __restrict__ bl2,
                      const float* __restrict__ Wl3, const float* __restrict__ bl3,
                      float* __restrict__ out) {
    __shared__ float t1[128], t2[64];
    int b = blockIdx.x; int t = threadIdx.x;        // 128 threads
    float s = bl1[t];
    for (int k = 0; k < 256; k++) s = fmaf(G[b * 256 + k], Wl1[k * 128 + t], s);
    t1[t] = fmaxf(s, 0.f);
    __syncthreads();
    if (t < 64) {
        float s2 = bl2[t];
        for (int k = 0; k < 128; k++) s2 = fmaf(t1[k], Wl2[k * 64 + t], s2);
        t2[t] = fmaxf(s2, 0.f);
    }
    __syncthreads();
    if (t < 2) {
        float s3 = bl3[t];
        for (int k = 0; k < 64; k++) s3 = fmaf(t2[k], Wl3[k * 2 + t], s3);
        out[b * 2 + t] = s3;
    }
}

// ---------------- launch ----------------
extern "C" void kernel_launch(void* const* d_in, const int* in_sizes, int n_in,
                              void* d_out, int out_size, void* d_ws, size_t ws_size,
                              hipStream_t stream) {
    const float* x       = (const float*)d_in[0];
    const int*   src_all = (const int*)d_in[1];
    const int*   dst_all = (const int*)d_in[2];
    const int*   src_c1  = (const int*)d_in[3];
    const int*   dst_c1  = (const int*)d_in[4];
    const int*   src_c2  = (const int*)d_in[5];
    const int*   dst_c2  = (const int*)d_in[6];
    const float* W1 = (const float*)d_in[7];   const float* b1 = (const float*)d_in[8];
    const float* W2 = (const float*)d_in[9];   const float* b2 = (const float*)d_in[10];
    const float* W3 = (const float*)d_in[11];  const float* b3 = (const float*)d_in[12];
    const float* Wg_att = (const float*)d_in[13];
    const float* Wal = (const float*)d_in[14]; const float* bal = (const float*)d_in[15];
    const float* Wf  = (const float*)d_in[16]; const float* bf  = (const float*)d_in[17];
    const float* Wg_fin = (const float*)d_in[18];
    const float* Wl1 = (const float*)d_in[19]; const float* bl1 = (const float*)d_in[20];
    const float* Wl2 = (const float*)d_in[21]; const float* bl2 = (const float*)d_in[22];
    const float* Wl3 = (const float*)d_in[23]; const float* bl3 = (const float*)d_in[24];
    float* out = (float*)d_out;

    // ---- workspace layout (floats) ----
    float* f = (float*)d_ws;
    size_t o = 0;
    float* XC   = f + o; o += (size_t)NN * 384;     // 96 MB
    float* SCR  = f + o; o += (size_t)NN * 128;     // 32 MB  xw scratch; later P + XWP
    float* H1P  = f + o; o += (size_t)NP * 128;
    float* H2P  = f + o; o += (size_t)NP * 128;
    int* ROWSTART = (int*)(f + o); o += 65552;      // reused as pooled rowstart later
    int* CSRC     = (int*)(f + o); o += EALL;       // reused as pooled CSR edges later
    int* CNT      = (int*)(f + o); o += NN;
    int* BSUM     = (int*)(f + o); o += 256;
    float* DIS    = f + o; o += NN;
    float* MEAN12 = f + o; o += 128 * 384;
    float* C12    = f + o; o += 128 * 384;
    float* ALPHA  = f + o; o += NN;
    float* GP     = f + o; o += 128 * 384;
    float* PV     = f + o; o += 64 * 768;
    float* PNORM  = f + o; o += 128;
    float* SC1    = f + o; o += 32768;
    float* SC2    = f + o; o += 32768;
    int* SEL1     = (int*)(f + o); o += 16384;
    int* SEL2     = (int*)(f + o); o += 16384;
    int* NMAP1    = (int*)(f + o); o += 32768;
    int* NMAP2    = (int*)(f + o); o += 32768;
    int* CNTP     = (int*)(f + o); o += 16384;
    float* DISP1  = f + o; o += 16384;
    float* DISP2  = f + o; o += 16384;
    float* MEANF  = f + o; o += 64 * 128;
    float* CFIN   = f + o; o += 64 * 128;
    float* ALF    = f + o; o += 16384;
    float* G12    = f + o; o += 64 * 256;
    size_t needed_bytes = o * sizeof(float);
    if (ws_size < needed_bytes) return;

    float* P1  = SCR;                      // 16384*384
    float* XWP = SCR + (size_t)NP * 384;   // 16384*128
    int* ROWSTP = ROWSTART;                // pooled rowstart (16385) reuses full rowstart
    int* CSRE   = CSRC;                    // pooled CSR edge list reuses full CSR

    // ---- full-graph CSR + degrees ----
    hipMemsetAsync(CNT, 0, NN * sizeof(int), stream);
    k_count<<<EALL / 256, 256, 0, stream>>>(dst_all, EALL, CNT);
    k_dis<<<NN / 256, 256, 0, stream>>>(CNT, DIS, NN);
    k_blocksum<<<256, 256, 0, stream>>>(CNT, BSUM);
    k_scan_bsum<<<1, 256, 0, stream>>>(BSUM, 256);
    k_scan_final<<<256, 256, 0, stream>>>(CNT, BSUM, ROWSTART, NN);
    hipMemsetAsync(CNT, 0, NN * sizeof(int), stream);
    k_csr_scatter<<<EALL / 256, 256, 0, stream>>>(src_all, dst_all, EALL, ROWSTART, CNT, CSRC);

    // ---- 3 GCN layers into XC columns ----
    k_gemm_tile<128><<<NN / 128, 256, 0, stream>>>(x, 128, W1, SCR, NN);
    k_aggregate4<<<NN / 8, 256, 0, stream>>>(SCR, DIS, ROWSTART, CSRC, b1, XC, 0);
    k_gemm_tile<128><<<NN / 128, 256, 0, stream>>>(XC + 0, 384, W2, SCR, NN);
    k_aggregate4<<<NN / 8, 256, 0, stream>>>(SCR, DIS, ROWSTART, CSRC, b2, XC, 128);
    k_gemm_tile<128><<<NN / 128, 256, 0, stream>>>(XC + 128, 384, W3, SCR, NN);
    k_aggregate4<<<NN / 8, 256, 0, stream>>>(SCR, DIS, ROWSTART, CSRC, b3, XC, 256);

    // ---- attention pool over communities ----
    k_mean12<<<128, 384, 0, stream>>>(XC, MEAN12);
    k_c12<<<128, 384, 0, stream>>>(MEAN12, Wg_att, C12);
    k_alpha12<<<NN / 4, 256, 0, stream>>>(XC, C12, ALPHA);
    k_gp<<<128, 384, 0, stream>>>(XC, ALPHA, GP);
    k_pv<<<64, 768, 0, stream>>>(GP, Wal, bal, PV);
    k_pnorm<<<128, 64, 0, stream>>>(PV, PNORM);

    // ---- scores + top-K per batch ----
    k_score<<<32768 / 4, 256, 0, stream>>>(XC, PV, PNORM, SC1, 0);
    k_score<<<32768 / 4, 256, 0, stream>>>(XC, PV, PNORM, SC2, 1);
    k_topk<<<64, 256, 0, stream>>>(SC1, SEL1, NMAP1);
    k_topk<<<64, 256, 0, stream>>>(SC2, SEL2, NMAP2);

    // ---- pooled GCN, community 1 (CSR-gather, no float atomics) ----
    k_gather<<<NP, 384, 0, stream>>>(XC, SC1, SEL1, P1, 0);
    hipMemsetAsync(CNTP, 0, NP * sizeof(int), stream);
    k_pooled_cnt<<<EC / 256, 256, 0, stream>>>(src_c1, dst_c1, NMAP1, CNTP);
    k_dis<<<NP / 256, 256, 0, stream>>>(CNTP, DISP1, NP);
    k_blocksum<<<NP / 256, 256, 0, stream>>>(CNTP, BSUM);
    k_scan_bsum<<<1, 256, 0, stream>>>(BSUM, NP / 256);
    k_scan_final<<<NP / 256, 256, 0, stream>>>(CNTP, BSUM, ROWSTP, NP);
    hipMemsetAsync(CNTP, 0, NP * sizeof(int), stream);
    k_csr_scatter_pooled<<<EC / 256, 256, 0, stream>>>(src_c1, dst_c1, NMAP1, ROWSTP, CNTP, CSRE);
    k_gemm_tile<384><<<NP / 128, 256, 0, stream>>>(P1, 384, Wf, XWP, NP);
    k_aggregate_pooled<<<NP / 8, 256, 0, stream>>>(XWP, DISP1, ROWSTP, CSRE, bf, H1P);

    // ---- pooled GCN, community 2 ----
    k_gather<<<NP, 384, 0, stream>>>(XC, SC2, SEL2, P1, 1);
    hipMemsetAsync(CNTP, 0, NP * sizeof(int), stream);
    k_pooled_cnt<<<EC / 256, 256, 0, stream>>>(src_c2, dst_c2, NMAP2, CNTP);
    k_dis<<<NP / 256, 256, 0, stream>>>(CNTP, DISP2, NP);
    k_blocksum<<<NP / 256, 256, 0, stream>>>(CNTP, BSUM);
    k_scan_bsum<<<1, 256, 0, stream>>>(BSUM, NP / 256);
    k_scan_final<<<NP / 256, 256, 0, stream>>>(CNTP, BSUM, ROWSTP, NP);
    hipMemsetAsync(CNTP, 0, NP * sizeof(int), stream);
    k_csr_scatter_pooled<<<EC / 256, 256, 0, stream>>>(src_c2, dst_c2, NMAP2, ROWSTP, CNTP, CSRE);
    k_gemm_tile<384><<<NP / 128, 256, 0, stream>>>(P1, 384, Wf, XWP, NP);
    k_aggregate_pooled<<<NP / 8, 256, 0, stream>>>(XWP, DISP2, ROWSTP, CSRE, bf, H2P);

    // ---- final attention pools ----
    k_meanf<<<64, 128, 0, stream>>>(H1P, MEANF);
    k_cfin<<<64, 128, 0, stream>>>(MEANF, Wg_fin, CFIN);
    k_alphaf<<<NP / 4, 256, 0, stream>>>(H1P, CFIN, ALF);
    k_gfin<<<64, 128, 0, stream>>>(H1P, ALF, G12, 0);

    k_meanf<<<64, 128, 0, stream>>>(H2P, MEANF);
    k_cfin<<<64, 128, 0, stream>>>(MEANF, Wg_fin, CFIN);
    k_alphaf<<<NP / 4, 256, 0, stream>>>(H2P, CFIN, ALF);
    k_gfin<<<64, 128, 0, stream>>>(H2P, ALF, G12, 128);

    // ---- MLP head ----
    k_mlp<<<64, 128, 0, stream>>>(G12, Wl1, bl1, Wl2, bl2, Wl3, bl3, out);
}

// Round 3
// 747.003 us; speedup vs baseline: 3.3645x; 1.3851x over previous
//
#include <hip/hip_runtime.h>
#include <math.h>

// ---------------- constants ----------------
constexpr int BB   = 64;
constexpr int NPB  = 1024;            // nodes per batch graph (N1+N2)
constexpr int NN   = BB * NPB;        // 65536 total nodes
constexpr int EALL = 1048576;         // total edges (both communities)
constexpr int EC   = 524288;          // edges per community
constexpr int KTOP = 256;             // K1 == K2
constexpr int NP   = BB * KTOP;       // 16384 pooled nodes per community
constexpr int NP2  = 2 * NP;          // 32768 pooled nodes total

// ---------------- graph prep ----------------
__global__ void k_count(const int* __restrict__ dst, int n, int* cnt) {
    int i = blockIdx.x * blockDim.x + threadIdx.x;
    if (i < n) atomicAdd(&cnt[dst[i]], 1);
}

__global__ void k_dis(const int* __restrict__ cnt, float* __restrict__ dis, int n) {
    int i = blockIdx.x * blockDim.x + threadIdx.x;
    if (i < n) dis[i] = 1.0f / sqrtf((float)cnt[i] + 1.0f);
}

__global__ void k_blocksum(const int* __restrict__ cnt, int* __restrict__ bsum) {
    __shared__ int s[256];
    int i = blockIdx.x * 256 + threadIdx.x;
    s[threadIdx.x] = cnt[i];
    __syncthreads();
    for (int st = 128; st > 0; st >>= 1) {
        if (threadIdx.x < st) s[threadIdx.x] += s[threadIdx.x + st];
        __syncthreads();
    }
    if (threadIdx.x == 0) bsum[blockIdx.x] = s[0];
}

__global__ void k_scan_bsum(int* bsum, int g) {
    __shared__ int s[256];
    int t = threadIdx.x;
    s[t] = (t < g) ? bsum[t] : 0;
    __syncthreads();
    if (t == 0) {
        int acc = 0;
        for (int i = 0; i < g; i++) { int v = s[i]; s[i] = acc; acc += v; }
    }
    __syncthreads();
    if (t < g) bsum[t] = s[t];
}

__global__ void k_scan_final(const int* __restrict__ cnt, const int* __restrict__ bsum,
                             int* __restrict__ rowstart, int ntot) {
    __shared__ int s[256];
    int i = blockIdx.x * 256 + threadIdx.x;
    int myc = cnt[i];
    s[threadIdx.x] = myc;
    __syncthreads();
    if (threadIdx.x == 0) {
        int acc = bsum[blockIdx.x];
        for (int j = 0; j < 256; j++) { int v = s[j]; s[j] = acc; acc += v; }
    }
    __syncthreads();
    rowstart[i] = s[threadIdx.x];
    if (i == ntot - 1) rowstart[ntot] = s[threadIdx.x] + myc;
}

__global__ void k_csr_scatter(const int* __restrict__ src, const int* __restrict__ dst, int n,
                              const int* __restrict__ rowstart, int* cursor, int* __restrict__ csrc) {
    int i = blockIdx.x * blockDim.x + threadIdx.x;
    if (i < n) {
        int d = dst[i];
        int p = atomicAdd(&cursor[d], 1);
        csrc[rowstart[d] + p] = src[i];
    }
}

// both communities in one dispatch; nmap holds GLOBAL pooled ids (or -1)
__global__ void k_pooled_cnt_both(const int* __restrict__ s1, const int* __restrict__ d1,
                                  const int* __restrict__ s2, const int* __restrict__ d2,
                                  const int* __restrict__ nmap, int* cnt) {
    int e2 = blockIdx.x * blockDim.x + threadIdx.x;   // 0..2EC-1
    int comm = e2 >= EC;
    int el = e2 & (EC - 1);
    const int* ss = comm ? s2 : s1;
    const int* dd = comm ? d2 : d1;
    const int* nm = nmap + comm * 32768;
    int r = nm[ss[el]], c = nm[dd[el]];
    if (r >= 0 && c >= 0) atomicAdd(&cnt[c], 1);
}

__global__ void k_pooled_scatter_both(const int* __restrict__ s1, const int* __restrict__ d1,
                                      const int* __restrict__ s2, const int* __restrict__ d2,
                                      const int* __restrict__ nmap, const int* __restrict__ rowstart,
                                      int* cursor, int* __restrict__ csre) {
    int e2 = blockIdx.x * blockDim.x + threadIdx.x;
    int comm = e2 >= EC;
    int el = e2 & (EC - 1);
    const int* ss = comm ? s2 : s1;
    const int* dd = comm ? d2 : d1;
    const int* nm = nmap + comm * 32768;
    int r = nm[ss[el]], c = nm[dd[el]];
    if (r >= 0 && c >= 0) {
        int p = atomicAdd(&cursor[c], 1);
        csre[rowstart[c] + p] = r;
    }
}

// ---------------- GEMM: C[M x 128] = A[M x KDIM] @ W[KDIM x 128], row-scaled ----------------
template <int KDIM>
__global__ __launch_bounds__(256) void k_gemm_tile(const float* __restrict__ A, int lda,
                                                   const float* __restrict__ W,
                                                   const float* __restrict__ rowscale,
                                                   float* __restrict__ C, int M) {
    __shared__ float As[32][136];
    __shared__ float Ws[32 * 128];
    const int tid  = threadIdx.x;
    const int c0 = (tid & 15) * 8;
    const int r0 = (tid >> 4) * 8;
    const int row0 = blockIdx.x * 128;
    const int arow = tid >> 1;
    const int aq   = tid & 1;

    float acc[8][8];
#pragma unroll
    for (int i = 0; i < 8; i++)
#pragma unroll
        for (int j = 0; j < 8; j++) acc[i][j] = 0.f;

    for (int k0 = 0; k0 < KDIM; k0 += 32) {
        __syncthreads();
        const float* Ap = A + (size_t)(row0 + arow) * lda + k0;
#pragma unroll
        for (int qq = 0; qq < 4; qq++) {
            int kk = (aq + 2 * qq) * 4;
            float4 av = *(const float4*)(Ap + kk);
            As[kk + 0][arow] = av.x;
            As[kk + 1][arow] = av.y;
            As[kk + 2][arow] = av.z;
            As[kk + 3][arow] = av.w;
        }
#pragma unroll
        for (int q = 0; q < 4; q++) {
            int f = tid + 256 * q;
            float4 wv = *(const float4*)(W + (size_t)k0 * 128 + f * 4);
            *(float4*)&Ws[f * 4] = wv;
        }
        __syncthreads();
#pragma unroll 2
        for (int kk = 0; kk < 32; kk++) {
            float4 a0 = *(const float4*)&As[kk][r0];
            float4 a1 = *(const float4*)&As[kk][r0 + 4];
            float4 b0 = *(const float4*)&Ws[kk * 128 + c0];
            float4 b1 = *(const float4*)&Ws[kk * 128 + c0 + 4];
            float a[8] = {a0.x, a0.y, a0.z, a0.w, a1.x, a1.y, a1.z, a1.w};
            float b[8] = {b0.x, b0.y, b0.z, b0.w, b1.x, b1.y, b1.z, b1.w};
#pragma unroll
            for (int i = 0; i < 8; i++)
#pragma unroll
                for (int j = 0; j < 8; j++)
                    acc[i][j] = fmaf(a[i], b[j], acc[i][j]);
        }
    }
#pragma unroll
    for (int i = 0; i < 8; i++) {
        int row = row0 + r0 + i;
        if (row < M) {
            float sc = rowscale[row];
            float4 o0 = {acc[i][0]*sc, acc[i][1]*sc, acc[i][2]*sc, acc[i][3]*sc};
            float4 o1 = {acc[i][4]*sc, acc[i][5]*sc, acc[i][6]*sc, acc[i][7]*sc};
            *(float4*)(C + (size_t)row * 128 + c0) = o0;
            *(float4*)(C + (size_t)row * 128 + c0 + 4) = o1;
        }
    }
}

// pooled GEMM: A rows gathered from XC via sel, scaled by sigmoid(score); KDIM=384
__global__ __launch_bounds__(256) void k_gemm_gather(const float* __restrict__ XC,
                                                     const int* __restrict__ sel,
                                                     const float* __restrict__ SC,
                                                     const float* __restrict__ rowscale,
                                                     const float* __restrict__ W,
                                                     float* __restrict__ C) {
    __shared__ float As[32][136];
    __shared__ float Ws[32 * 128];
    const int tid  = threadIdx.x;
    const int c0 = (tid & 15) * 8;
    const int r0 = (tid >> 4) * 8;
    const int row0 = blockIdx.x * 128;
    const int arow = tid >> 1;
    const int aq   = tid & 1;

    // per-thread gathered row + sigmoid scale (computed once)
    int n = row0 + arow;
    int comm = n >= NP;
    int nl = n - (comm ? NP : 0);
    int b = nl >> 8;
    int old = sel[n];
    const float* srow = XC + (size_t)(b * NPB + comm * 512 + old) * 384;
    float scv = SC[comm * 32768 + b * 512 + old];
    float sg = 1.f / (1.f + expf(-scv));

    float acc[8][8];
#pragma unroll
    for (int i = 0; i < 8; i++)
#pragma unroll
        for (int j = 0; j < 8; j++) acc[i][j] = 0.f;

    for (int k0 = 0; k0 < 384; k0 += 32) {
        __syncthreads();
#pragma unroll
        for (int qq = 0; qq < 4; qq++) {
            int kk = (aq + 2 * qq) * 4;
            float4 av = *(const float4*)(srow + k0 + kk);
            As[kk + 0][arow] = av.x * sg;
            As[kk + 1][arow] = av.y * sg;
            As[kk + 2][arow] = av.z * sg;
            As[kk + 3][arow] = av.w * sg;
        }
#pragma unroll
        for (int q = 0; q < 4; q++) {
            int f = tid + 256 * q;
            float4 wv = *(const float4*)(W + (size_t)k0 * 128 + f * 4);
            *(float4*)&Ws[f * 4] = wv;
        }
        __syncthreads();
#pragma unroll 2
        for (int kk = 0; kk < 32; kk++) {
            float4 a0 = *(const float4*)&As[kk][r0];
            float4 a1 = *(const float4*)&As[kk][r0 + 4];
            float4 b0 = *(const float4*)&Ws[kk * 128 + c0];
            float4 b1 = *(const float4*)&Ws[kk * 128 + c0 + 4];
            float a[8] = {a0.x, a0.y, a0.z, a0.w, a1.x, a1.y, a1.z, a1.w};
            float b[8] = {b0.x, b0.y, b0.z, b0.w, b1.x, b1.y, b1.z, b1.w};
#pragma unroll
            for (int i = 0; i < 8; i++)
#pragma unroll
                for (int j = 0; j < 8; j++)
                    acc[i][j] = fmaf(a[i], b[j], acc[i][j]);
        }
    }
#pragma unroll
    for (int i = 0; i < 8; i++) {
        int row = row0 + r0 + i;
        float sc = rowscale[row];
        float4 o0 = {acc[i][0]*sc, acc[i][1]*sc, acc[i][2]*sc, acc[i][3]*sc};
        float4 o1 = {acc[i][4]*sc, acc[i][5]*sc, acc[i][6]*sc, acc[i][7]*sc};
        *(float4*)(C + (size_t)row * 128 + c0) = o0;
        *(float4*)(C + (size_t)row * 128 + c0 + 4) = o1;
    }
}

// ---------------- GCN aggregation (CSR gather, xw pre-scaled by dis[src]) ----------------
// XCD-aware swizzle: group = 512 contiguous nodes (one batch-community), 64 blocks/group.
__global__ void k_aggregate4(const float* __restrict__ xwsc, const float* __restrict__ dis,
                             const int* __restrict__ rowstart, const int* __restrict__ csrc,
                             const float* __restrict__ bias, float* __restrict__ XC, int colbase) {
    int xcd  = blockIdx.x & 7;
    int slot = blockIdx.x >> 3;            // 0..1023
    int g    = ((slot >> 6) << 3) | xcd;   // 0..127
    int node = g * 512 + (slot & 63) * 8 + (threadIdx.x >> 5);
    int l    = threadIdx.x & 31;
    const float4* xw4 = (const float4*)xwsc;
    float4 acc = xw4[(size_t)node * 32 + l];
    int e0 = rowstart[node], e1 = rowstart[node + 1];
    for (int e = e0; e < e1; e++) {
        int s = csrc[e];
        float4 u = xw4[(size_t)s * 32 + l];
        acc.x += u.x; acc.y += u.y; acc.z += u.z; acc.w += u.w;
    }
    float di = dis[node];
    float4 b4 = ((const float4*)bias)[l];
    acc.x = fmaxf(acc.x * di + b4.x, 0.f);
    acc.y = fmaxf(acc.y * di + b4.y, 0.f);
    acc.z = fmaxf(acc.z * di + b4.z, 0.f);
    acc.w = fmaxf(acc.w * di + b4.w, 0.f);
    *(float4*)(XC + (size_t)node * 384 + colbase + l * 4) = acc;
}

// pooled variant: 2NP nodes, group = 256 contiguous nodes, 32 blocks/group
__global__ void k_aggregate_pooled(const float* __restrict__ xwsc, const float* __restrict__ disp,
                                   const int* __restrict__ rowstart, const int* __restrict__ csre,
                                   const float* __restrict__ bias, float* __restrict__ H) {
    int xcd  = blockIdx.x & 7;
    int slot = blockIdx.x >> 3;            // 0..511
    int g    = ((slot >> 5) << 3) | xcd;   // 0..127
    int node = g * 256 + (slot & 31) * 8 + (threadIdx.x >> 5);
    int l    = threadIdx.x & 31;
    const float4* xw4 = (const float4*)xwsc;
    float4 acc = xw4[(size_t)node * 32 + l];
    int e0 = rowstart[node], e1 = rowstart[node + 1];
    for (int e = e0; e < e1; e++) {
        int r = csre[e];
        float4 u = xw4[(size_t)r * 32 + l];
        acc.x += u.x; acc.y += u.y; acc.z += u.z; acc.w += u.w;
    }
    float di = disp[node];
    float4 b4 = ((const float4*)bias)[l];
    acc.x = fmaxf(acc.x * di + b4.x, 0.f);
    acc.y = fmaxf(acc.y * di + b4.y, 0.f);
    acc.z = fmaxf(acc.z * di + b4.z, 0.f);
    acc.w = fmaxf(acc.w * di + b4.w, 0.f);
    *(float4*)(H + (size_t)node * 128 + l * 4) = acc;
}

// ---------------- attention pool stage 1 ----------------
// mean partials: 4 blocks per contiguous group; MPART indexed by seg_id = comm*64+b
__global__ void k_mean_part(const float* __restrict__ XC, float* __restrict__ mpart) {
    int blk = blockIdx.x;              // 0..511
    int gc = blk >> 2, p = blk & 3;
    int seg = ((gc & 1) << 6) | (gc >> 1);
    int c = threadIdx.x;               // 0..383
    int base = gc * 512 + p * 128;
    float s = 0.f;
    for (int i = 0; i < 128; i++) s += XC[(size_t)(base + i) * 384 + c];
    mpart[(size_t)(seg * 4 + p) * 384 + c] = s;
}

__global__ void k_c12(const float* __restrict__ mpart, const float* __restrict__ Wg,
                      float* __restrict__ c12) {
    __shared__ float ms[384];
    int seg = blockIdx.x; int c = threadIdx.x;   // 384 threads
    ms[c] = (mpart[(size_t)(seg * 4 + 0) * 384 + c] + mpart[(size_t)(seg * 4 + 1) * 384 + c] +
             mpart[(size_t)(seg * 4 + 2) * 384 + c] + mpart[(size_t)(seg * 4 + 3) * 384 + c]) *
            (1.0f / 512.0f);
    __syncthreads();
    float s = 0.f;
    for (int k = 0; k < 384; k++) s = fmaf(ms[k], Wg[(size_t)k * 384 + c], s);
    c12[seg * 384 + c] = tanhf(s);
}

// fused alpha + gp: one pass over XC, register accumulators, atomicAdd into GP (pre-zeroed)
__global__ __launch_bounds__(256) void k_attpool1(const float* __restrict__ XC,
                                                  const float* __restrict__ C12,
                                                  float* __restrict__ GP) {
    __shared__ float gps[4][384];
    int blk = blockIdx.x;              // 0..511 (4 per group)
    int gc = blk >> 2, q = blk & 3;
    int seg = ((gc & 1) << 6) | (gc >> 1);
    int w = threadIdx.x >> 6, l = threadIdx.x & 63;
    const float* c12r = C12 + seg * 384;
    float4 cr0 = *(const float4*)(c12r + 4 * l);
    float4 cr1 = (l < 32) ? *(const float4*)(c12r + 256 + 4 * l) : float4{0.f,0.f,0.f,0.f};
    float4 a0 = {0.f,0.f,0.f,0.f}, a1 = {0.f,0.f,0.f,0.f};
    int base = gc * 512 + q * 128 + w * 32;
    for (int it = 0; it < 32; it++) {
        const float* xr = XC + (size_t)(base + it) * 384;
        float4 v0 = *(const float4*)(xr + 4 * l);
        float4 v1 = (l < 32) ? *(const float4*)(xr + 256 + 4 * l) : float4{0.f,0.f,0.f,0.f};
        float s = v0.x*cr0.x + v0.y*cr0.y + v0.z*cr0.z + v0.w*cr0.w
                + v1.x*cr1.x + v1.y*cr1.y + v1.z*cr1.z + v1.w*cr1.w;
        for (int off = 32; off; off >>= 1) s += __shfl_xor(s, off);
        float al = 1.f / (1.f + expf(-s));
        a0.x += v0.x*al; a0.y += v0.y*al; a0.z += v0.z*al; a0.w += v0.w*al;
        a1.x += v1.x*al; a1.y += v1.y*al; a1.z += v1.z*al; a1.w += v1.w*al;
    }
    *(float4*)&gps[w][4 * l] = a0;
    if (l < 32) *(float4*)&gps[w][256 + 4 * l] = a1;
    __syncthreads();
    for (int c = threadIdx.x; c < 384; c += 256) {
        float s = gps[0][c] + gps[1][c] + gps[2][c] + gps[3][c];
        atomicAdd(&GP[seg * 384 + c], s);
    }
}

__global__ void k_pv(const float* __restrict__ gp, const float* __restrict__ Wal,
                     const float* __restrict__ bal, float* __restrict__ pv) {
    int row = blockIdx.x;               // 0..63
    int c   = threadIdx.x;              // 0..767
    float s = bal[c];
    for (int k = 0; k < 768; k++) {
        float v = (k < 384) ? gp[row * 384 + k] : gp[(64 + row) * 384 + (k - 384)];
        s = fmaf(v, Wal[(size_t)k * 768 + c], s);
    }
    pv[row * 768 + c] = s;
}

__global__ void k_pnorm(const float* __restrict__ pv, float* __restrict__ pnorm) {
    int id = blockIdx.x;                // 0..127 : comm = id>>6, b = id&63
    int lane = threadIdx.x;
    int h = id >> 6, b = id & 63;
    const float* p = pv + b * 768 + h * 384;
    float s = 0.f;
    for (int k = lane; k < 384; k += 64) s += p[k] * p[k];
    for (int off = 32; off; off >>= 1) s += __shfl_down(s, off);
    if (lane == 0) pnorm[id] = sqrtf(s);
}

// ---------------- scores (both communities) + per-batch top-K ----------------
__global__ void k_score(const float* __restrict__ XC, const float* __restrict__ pv,
                        const float* __restrict__ pnorm, float* __restrict__ sc) {
    int nl2 = blockIdx.x * 4 + (threadIdx.x >> 6);   // 0..65535
    int lane = threadIdx.x & 63;
    int comm = nl2 >> 15;
    int nl = nl2 & 32767;
    int b = nl >> 9; int i = nl & 511;
    const float* xr = XC + (size_t)(b * NPB + comm * 512 + i) * 384;
    const float* pr = pv + b * 768 + comm * 384;
    float4 x0 = *(const float4*)(xr + 4 * lane);
    float4 p0 = *(const float4*)(pr + 4 * lane);
    float s = x0.x*p0.x + x0.y*p0.y + x0.z*p0.z + x0.w*p0.w;
    if (lane < 32) {
        float4 x1 = *(const float4*)(xr + 256 + 4 * lane);
        float4 p1 = *(const float4*)(pr + 256 + 4 * lane);
        s += x1.x*p1.x + x1.y*p1.y + x1.z*p1.z + x1.w*p1.w;
    }
    for (int off = 32; off; off >>= 1) s += __shfl_down(s, off);
    if (lane == 0) sc[comm * 32768 + nl] = s / pnorm[comm * 64 + b];
}

__global__ void k_topk(const float* __restrict__ sc, int* __restrict__ sel, int* __restrict__ nmap) {
    __shared__ float sv[512];
    __shared__ int   si[512];
    int blk = blockIdx.x;               // 0..127 = comm*64 + b
    int t = threadIdx.x;                // 0..255
    sv[t] = sc[blk * 512 + t];             si[t] = t;
    sv[t + 256] = sc[blk * 512 + t + 256]; si[t + 256] = t + 256;
    __syncthreads();
    for (int k2 = 2; k2 <= 512; k2 <<= 1) {
        for (int j = k2 >> 1; j > 0; j >>= 1) {
            for (int i = t; i < 512; i += 256) {
                int l = i ^ j;
                if (l > i) {
                    bool desc = ((i & k2) == 0);
                    float a = sv[i], bb2 = sv[l];
                    bool sw = desc ? (a < bb2) : (a > bb2);
                    if (sw) {
                        sv[i] = bb2; sv[l] = a;
                        int tmp = si[i]; si[i] = si[l]; si[l] = tmp;
                    }
                }
            }
            __syncthreads();
        }
    }
    sel[blk * 256 + t] = si[t];                 // selected local idx (0..511)
    nmap[blk * 512 + si[t]] = blk * 256 + t;    // global pooled id
    nmap[blk * 512 + si[t + 256]] = -1;
}

// ---------------- final attention pools (2NP nodes, 128 segments of 256) ----------------
__global__ void k_meanf(const float* __restrict__ H, float* __restrict__ mean) {
    int b = blockIdx.x; int c = threadIdx.x;        // 128 blocks x 128 thr
    float s = 0.f;
    for (int i = 0; i < 256; i++) s += H[(size_t)(b * 256 + i) * 128 + c];
    mean[b * 128 + c] = s * (1.0f / 256.0f);
}

__global__ void k_cfin(const float* __restrict__ mean, const float* __restrict__ Wg,
                       float* __restrict__ cf) {
    __shared__ float ms[128];
    int b = blockIdx.x; int c = threadIdx.x;
    ms[c] = mean[b * 128 + c];
    __syncthreads();
    float s = 0.f;
    for (int k = 0; k < 128; k++) s = fmaf(ms[k], Wg[k * 128 + c], s);
    cf[b * 128 + c] = tanhf(s);
}

__global__ void k_alphaf(const float* __restrict__ H, const float* __restrict__ cf,
                         float* __restrict__ al) {
    int node = blockIdx.x * 4 + (threadIdx.x >> 6);
    int lane = threadIdx.x & 63;
    int b = node >> 8;
    float s = 0.f;
    if (lane < 32) {
        float4 h = *(const float4*)(H + (size_t)node * 128 + 4 * lane);
        float4 c = *(const float4*)(cf + b * 128 + 4 * lane);
        s = h.x*c.x + h.y*c.y + h.z*c.z + h.w*c.w;
    }
    for (int off = 32; off; off >>= 1) s += __shfl_down(s, off);
    if (lane == 0) al[node] = 1.f / (1.f + expf(-s));
}

__global__ void k_gfin(const float* __restrict__ H, const float* __restrict__ al,
                       float* __restrict__ g) {
    int seg = blockIdx.x; int c = threadIdx.x;      // 128 blocks x 128 thr
    int b = seg & 63, comm = seg >> 6;
    float s = 0.f;
    for (int i = 0; i < 256; i++) { int n = seg * 256 + i; s += H[(size_t)n * 128 + c] * al[n]; }
    g[b * 256 + comm * 128 + c] = s;
}

// ---------------- MLP head ----------------
__global__ void k_mlp(const float* __restrict__ G,
                      const float* __restrict__ Wl1, const float* __restrict__ bl1,
                      const float* __restrict__ Wl2, const float* __restrict__ bl2,
                      const float* __restrict__ Wl3, const float* __restrict__ bl3,
                      float* __restrict__ out) {
    __shared__ float t1[128], t2[64];
    int b = blockIdx.x; int t = threadIdx.x;        // 128 threads
    float s = bl1[t];
    for (int k = 0; k < 256; k++) s = fmaf(G[b * 256 + k], Wl1[k * 128 + t], s);
    t1[t] = fmaxf(s, 0.f);
    __syncthreads();
    if (t < 64) {
        float s2 = bl2[t];
        for (int k = 0; k < 128; k++) s2 = fmaf(t1[k], Wl2[k * 64 + t], s2);
        t2[t] = fmaxf(s2, 0.f);
    }
    __syncthreads();
    if (t < 2) {
        float s3 = bl3[t];
        for (int k = 0; k < 64; k++) s3 = fmaf(t2[k], Wl3[k * 2 + t], s3);
        out[b * 2 + t] = s3;
    }
}

// ---------------- launch ----------------
extern "C" void kernel_launch(void* const* d_in, const int* in_sizes, int n_in,
                              void* d_out, int out_size, void* d_ws, size_t ws_size,
                              hipStream_t stream) {
    const float* x       = (const float*)d_in[0];
    const int*   src_all = (const int*)d_in[1];
    const int*   dst_all = (const int*)d_in[2];
    const int*   src_c1  = (const int*)d_in[3];
    const int*   dst_c1  = (const int*)d_in[4];
    const int*   src_c2  = (const int*)d_in[5];
    const int*   dst_c2  = (const int*)d_in[6];
    const float* W1 = (const float*)d_in[7];   const float* b1 = (const float*)d_in[8];
    const float* W2 = (const float*)d_in[9];   const float* b2 = (const float*)d_in[10];
    const float* W3 = (const float*)d_in[11];  const float* b3 = (const float*)d_in[12];
    const float* Wg_att = (const float*)d_in[13];
    const float* Wal = (const float*)d_in[14]; const float* bal = (const float*)d_in[15];
    const float* Wf  = (const float*)d_in[16]; const float* bf  = (const float*)d_in[17];
    const float* Wg_fin = (const float*)d_in[18];
    const float* Wl1 = (const float*)d_in[19]; const float* bl1 = (const float*)d_in[20];
    const float* Wl2 = (const float*)d_in[21]; const float* bl2 = (const float*)d_in[22];
    const float* Wl3 = (const float*)d_in[23]; const float* bl3 = (const float*)d_in[24];
    float* out = (float*)d_out;

    // ---- workspace layout (floats) ----
    float* f = (float*)d_ws;
    size_t o = 0;
    float* XC   = f + o; o += (size_t)NN * 384;     // 96 MB
    float* SCR  = f + o; o += (size_t)NN * 128;     // 32 MB  xw*dis; later XWP (2NP x 128)
    float* H    = f + o; o += (size_t)NP2 * 128;    // 16 MB  pooled conv output (both comms)
    int* ROWSTART = (int*)(f + o); o += 65552;      // full rowstart; later pooled rowstart
    int* CSRC     = (int*)(f + o); o += EALL;       // full CSR; later pooled CSR (<= EALL)
    int* CNT      = (int*)(f + o); o += NN;         // counts/cursor, full & pooled
    int* BSUM     = (int*)(f + o); o += 256;
    float* DIS    = f + o; o += NN;
    float* MPART  = f + o; o += 512 * 384;
    float* C12    = f + o; o += 128 * 384;
    float* GP     = f + o; o += 128 * 384;
    float* PV     = f + o; o += 64 * 768;
    float* PNORM  = f + o; o += 128;
    float* SC     = f + o; o += 65536;
    int* SEL      = (int*)(f + o); o += NP2;
    int* NMAP     = (int*)(f + o); o += 65536;
    float* DISP   = f + o; o += NP2;
    float* MEANF  = f + o; o += 128 * 128;
    float* CFIN   = f + o; o += 128 * 128;
    float* ALF    = f + o; o += NP2;
    float* G12    = f + o; o += 64 * 256;
    size_t needed_bytes = o * sizeof(float);
    if (ws_size < needed_bytes) return;

    float* XWP = SCR;                   // pooled xw*sig*dis, 2NP x 128 (reuses SCR)

    // ---- full-graph CSR + degrees ----
    hipMemsetAsync(CNT, 0, NN * sizeof(int), stream);
    k_count<<<EALL / 256, 256, 0, stream>>>(dst_all, EALL, CNT);
    k_dis<<<NN / 256, 256, 0, stream>>>(CNT, DIS, NN);
    k_blocksum<<<256, 256, 0, stream>>>(CNT, BSUM);
    k_scan_bsum<<<1, 256, 0, stream>>>(BSUM, 256);
    k_scan_final<<<256, 256, 0, stream>>>(CNT, BSUM, ROWSTART, NN);
    hipMemsetAsync(CNT, 0, NN * sizeof(int), stream);
    k_csr_scatter<<<EALL / 256, 256, 0, stream>>>(src_all, dst_all, EALL, ROWSTART, CNT, CSRC);

    // ---- 3 GCN layers into XC columns (xw pre-scaled by dis[row]) ----
    k_gemm_tile<128><<<NN / 128, 256, 0, stream>>>(x, 128, W1, DIS, SCR, NN);
    k_aggregate4<<<NN / 8, 256, 0, stream>>>(SCR, DIS, ROWSTART, CSRC, b1, XC, 0);
    k_gemm_tile<128><<<NN / 128, 256, 0, stream>>>(XC + 0, 384, W2, DIS, SCR, NN);
    k_aggregate4<<<NN / 8, 256, 0, stream>>>(SCR, DIS, ROWSTART, CSRC, b2, XC, 128);
    k_gemm_tile<128><<<NN / 128, 256, 0, stream>>>(XC + 128, 384, W3, DIS, SCR, NN);
    k_aggregate4<<<NN / 8, 256, 0, stream>>>(SCR, DIS, ROWSTART, CSRC, b3, XC, 256);

    // ---- attention pool over communities ----
    k_mean_part<<<512, 384, 0, stream>>>(XC, MPART);
    k_c12<<<128, 384, 0, stream>>>(MPART, Wg_att, C12);
    hipMemsetAsync(GP, 0, 128 * 384 * sizeof(float), stream);
    k_attpool1<<<512, 256, 0, stream>>>(XC, C12, GP);
    k_pv<<<64, 768, 0, stream>>>(GP, Wal, bal, PV);
    k_pnorm<<<128, 64, 0, stream>>>(PV, PNORM);

    // ---- scores + top-K per (batch, community) ----
    k_score<<<65536 / 4, 256, 0, stream>>>(XC, PV, PNORM, SC);
    k_topk<<<128, 256, 0, stream>>>(SC, SEL, NMAP);

    // ---- pooled graph build (both communities) ----
    hipMemsetAsync(CNT, 0, NP2 * sizeof(int), stream);
    k_pooled_cnt_both<<<2 * EC / 256, 256, 0, stream>>>(src_c1, dst_c1, src_c2, dst_c2, NMAP, CNT);
    k_dis<<<NP2 / 256, 256, 0, stream>>>(CNT, DISP, NP2);
    k_blocksum<<<NP2 / 256, 256, 0, stream>>>(CNT, BSUM);
    k_scan_bsum<<<1, 256, 0, stream>>>(BSUM, NP2 / 256);
    k_scan_final<<<NP2 / 256, 256, 0, stream>>>(CNT, BSUM, ROWSTART, NP2);
    hipMemsetAsync(CNT, 0, NP2 * sizeof(int), stream);
    k_pooled_scatter_both<<<2 * EC / 256, 256, 0, stream>>>(src_c1, dst_c1, src_c2, dst_c2,
                                                            NMAP, ROWSTART, CNT, CSRC);

    // ---- pooled GCN (gathered GEMM + CSR aggregate), both communities ----
    k_gemm_gather<<<NP2 / 128, 256, 0, stream>>>(XC, SEL, SC, DISP, Wf, XWP);
    k_aggregate_pooled<<<NP2 / 8, 256, 0, stream>>>(XWP, DISP, ROWSTART, CSRC, bf, H);

    // ---- final attention pools (both communities in one pass) ----
    k_meanf<<<128, 128, 0, stream>>>(H, MEANF);
    k_cfin<<<128, 128, 0, stream>>>(MEANF, Wg_fin, CFIN);
    k_alphaf<<<NP2 / 4, 256, 0, stream>>>(H, CFIN, ALF);
    k_gfin<<<128, 128, 0, stream>>>(H, ALF, G12);

    // ---- MLP head ----
    k_mlp<<<64, 128, 0, stream>>>(G12, Wl1, bl1, Wl2, bl2, Wl3, bl3, out);
}

// Round 4
// 631.063 us; speedup vs baseline: 3.9826x; 1.1837x over previous
//
#include <hip/hip_runtime.h>
#include <math.h>

// ---------------- constants ----------------
constexpr int BB   = 64;
constexpr int NPB  = 1024;            // nodes per batch graph (N1+N2)
constexpr int NN   = BB * NPB;        // 65536 total nodes
constexpr int EALL = 1048576;         // total edges (both communities)
constexpr int EC   = 524288;          // edges per community
constexpr int EPG  = 8192;            // edges per (batch,community) group == N1*DEG
constexpr int KTOP = 256;             // K1 == K2
constexpr int NP   = BB * KTOP;       // 16384 pooled nodes per community
constexpr int NP2  = 2 * NP;          // 32768 pooled nodes total

__device__ __forceinline__ int wswz(int q) { return q ^ ((q >> 3) & 1); }

// ---------------- full-graph CSR build: per-group LDS counting sort ----------------
// group g (0..127): b = g>>1, c = g&1; nodes [g*512, g*512+512);
// edges [c*EC + b*8192, +8192); CSR region [g*8192, +8192).
__global__ __launch_bounds__(256) void k_build_csr(const int* __restrict__ src_all,
                                                   const int* __restrict__ dst_all,
                                                   int* __restrict__ rowstart,
                                                   int* __restrict__ csrc,
                                                   float* __restrict__ dis) {
    __shared__ int cnt[512];
    __shared__ int rs[512];
    __shared__ int wsum[4];
    __shared__ int stage[EPG];
    const int g = blockIdx.x;
    const int b = g >> 1, c = g & 1;
    const int ebase  = c * EC + b * EPG;
    const int region = g * EPG;
    const int nbase  = g * 512;
    const int t = threadIdx.x;
    const int lane = t & 63, w = t >> 6;

    cnt[t] = 0; cnt[t + 256] = 0;
    __syncthreads();
    for (int i = 0; i < 32; i++) {
        int d = dst_all[ebase + t + 256 * i] & 511;
        atomicAdd(&cnt[d], 1);
    }
    __syncthreads();
    // exclusive scan of 512 counters (2 per thread)
    int v0 = cnt[2 * t], v1 = cnt[2 * t + 1];
    int p = v0 + v1;
    int incl = p;
    for (int off = 1; off < 64; off <<= 1) {
        int u = __shfl_up(incl, off);
        if (lane >= off) incl += u;
    }
    if (lane == 63) wsum[w] = incl;
    __syncthreads();
    int base = 0;
    for (int i = 0; i < w; i++) base += wsum[i];
    int excl = base + incl - p;
    rs[2 * t] = excl;
    rs[2 * t + 1] = excl + v0;
    // global rowstart + dis
    rowstart[nbase + 2 * t]     = region + excl;
    rowstart[nbase + 2 * t + 1] = region + excl + v0;
    dis[nbase + 2 * t]     = 1.0f / sqrtf((float)v0 + 1.0f);
    dis[nbase + 2 * t + 1] = 1.0f / sqrtf((float)v1 + 1.0f);
    if (g == 127 && t == 0) rowstart[NN] = EALL;
    __syncthreads();
    // scatter into LDS stage (rs doubles as cursor)
    for (int i = 0; i < 32; i++) {
        int e = ebase + t + 256 * i;
        int d = dst_all[e] & 511;
        int pp = atomicAdd(&rs[d], 1);
        stage[pp] = src_all[e];
    }
    __syncthreads();
    for (int i = 0; i < 32; i++)
        csrc[region + t + 256 * i] = stage[t + 256 * i];
}

// ---------------- pooled CSR build: per-group LDS counting sort (padded regions) ----------------
// group g (0..127): c = g>>6, b = g&63; pooled nodes [g*256, +256);
// candidate edges [b*8192, +8192) of community c; region [g*8192, +8192) (padded).
__global__ __launch_bounds__(256) void k_build_csr_pooled(const int* __restrict__ s1,
                                                          const int* __restrict__ d1,
                                                          const int* __restrict__ s2,
                                                          const int* __restrict__ d2,
                                                          const int* __restrict__ nmap,
                                                          int* __restrict__ rowstart,
                                                          int* __restrict__ cntp,
                                                          int* __restrict__ csre,
                                                          float* __restrict__ disp) {
    __shared__ int cnt[256];
    __shared__ int rs[256];
    __shared__ int wsum[4];
    __shared__ int stage[EPG];
    const int g = blockIdx.x;
    const int c = g >> 6, b = g & 63;
    const int* ss = c ? s2 : s1;
    const int* dd = c ? d2 : d1;
    const int* nm = nmap + c * 32768;
    const int ebase  = b * EPG;
    const int region = g * EPG;
    const int nbase  = g * 256;
    const int t = threadIdx.x;
    const int lane = t & 63, w = t >> 6;

    cnt[t] = 0;
    __syncthreads();
    for (int i = 0; i < 32; i++) {
        int e = ebase + t + 256 * i;
        int r = nm[ss[e]], cc = nm[dd[e]];
        if (r >= 0 && cc >= 0) atomicAdd(&cnt[cc & 255], 1);
    }
    __syncthreads();
    int v = cnt[t];
    int incl = v;
    for (int off = 1; off < 64; off <<= 1) {
        int u = __shfl_up(incl, off);
        if (lane >= off) incl += u;
    }
    if (lane == 63) wsum[w] = incl;
    __syncthreads();
    int base = 0;
    for (int i = 0; i < w; i++) base += wsum[i];
    int excl = base + incl - v;
    rs[t] = excl;
    rowstart[nbase + t] = region + excl;
    cntp[nbase + t] = v;
    disp[nbase + t] = 1.0f / sqrtf((float)v + 1.0f);
    __syncthreads();
    for (int i = 0; i < 32; i++) {
        int e = ebase + t + 256 * i;
        int r = nm[ss[e]], cc = nm[dd[e]];
        if (r >= 0 && cc >= 0) {
            int pp = atomicAdd(&rs[cc & 255], 1);
            stage[pp] = r;
        }
    }
    __syncthreads();
    for (int i = 0; i < 32; i++)
        csre[region + t + 256 * i] = stage[t + 256 * i];
}

// ---------------- GEMM: C[M x 128] = A[M x KDIM] @ W[KDIM x 128], row-scaled ----------------
template <int KDIM>
__global__ __launch_bounds__(256) void k_gemm_tile(const float* __restrict__ A, int lda,
                                                   const float* __restrict__ W,
                                                   const float* __restrict__ rowscale,
                                                   float* __restrict__ C, int M) {
    __shared__ float As[32][136];
    __shared__ float Ws[32 * 128];
    const int tid  = threadIdx.x;
    const int c0 = (tid & 15) * 8;
    const int r0 = (tid >> 4) * 8;
    const int row0 = blockIdx.x * 128;
    const int arow = tid >> 1;
    const int aq   = tid & 1;

    float acc[8][8];
#pragma unroll
    for (int i = 0; i < 8; i++)
#pragma unroll
        for (int j = 0; j < 8; j++) acc[i][j] = 0.f;

    for (int k0 = 0; k0 < KDIM; k0 += 32) {
        __syncthreads();
        const float* Ap = A + (size_t)(row0 + arow) * lda + k0;
#pragma unroll
        for (int qq = 0; qq < 4; qq++) {
            int kk = (aq + 2 * qq) * 4;
            float4 av = *(const float4*)(Ap + kk);
            As[kk + 0][arow] = av.x;
            As[kk + 1][arow] = av.y;
            As[kk + 2][arow] = av.z;
            As[kk + 3][arow] = av.w;
        }
#pragma unroll
        for (int q = 0; q < 4; q++) {
            int f = tid + 256 * q;
            int kk = f >> 5, qd = f & 31;
            float4 wv = *(const float4*)(W + (size_t)k0 * 128 + f * 4);
            *(float4*)&Ws[kk * 128 + wswz(qd) * 4] = wv;
        }
        __syncthreads();
#pragma unroll 2
        for (int kk = 0; kk < 32; kk++) {
            int q0 = c0 >> 2;
            float4 a0 = *(const float4*)&As[kk][r0];
            float4 a1 = *(const float4*)&As[kk][r0 + 4];
            float4 b0 = *(const float4*)&Ws[kk * 128 + wswz(q0) * 4];
            float4 b1 = *(const float4*)&Ws[kk * 128 + wswz(q0 + 1) * 4];
            float a[8] = {a0.x, a0.y, a0.z, a0.w, a1.x, a1.y, a1.z, a1.w};
            float b[8] = {b0.x, b0.y, b0.z, b0.w, b1.x, b1.y, b1.z, b1.w};
#pragma unroll
            for (int i = 0; i < 8; i++)
#pragma unroll
                for (int j = 0; j < 8; j++)
                    acc[i][j] = fmaf(a[i], b[j], acc[i][j]);
        }
    }
#pragma unroll
    for (int i = 0; i < 8; i++) {
        int row = row0 + r0 + i;
        if (row < M) {
            float sc = rowscale[row];
            float4 o0 = {acc[i][0]*sc, acc[i][1]*sc, acc[i][2]*sc, acc[i][3]*sc};
            float4 o1 = {acc[i][4]*sc, acc[i][5]*sc, acc[i][6]*sc, acc[i][7]*sc};
            *(float4*)(C + (size_t)row * 128 + c0) = o0;
            *(float4*)(C + (size_t)row * 128 + c0 + 4) = o1;
        }
    }
}

// pooled GEMM: A rows gathered from XC via sel, scaled by sigmoid(score); KDIM=384.
// 512 threads (8 waves/CU at 1 block/CU), 4x8 micro-tile.
__global__ __launch_bounds__(512) void k_gemm_gather(const float* __restrict__ XC,
                                                     const int* __restrict__ sel,
                                                     const float* __restrict__ SC,
                                                     const float* __restrict__ rowscale,
                                                     const float* __restrict__ W,
                                                     float* __restrict__ C) {
    __shared__ float As[32][136];
    __shared__ float Ws[32 * 128];
    const int tid  = threadIdx.x;
    const int c0 = (tid & 15) * 8;
    const int r0 = (tid >> 4) * 4;
    const int row0 = blockIdx.x * 128;
    const int arow = tid >> 2;
    const int aq   = tid & 3;

    int n = row0 + arow;
    int comm = n >= NP;
    int nl = n - (comm ? NP : 0);
    int b = nl >> 8;
    int old = sel[n];
    const float* srow = XC + (size_t)(b * NPB + comm * 512 + old) * 384;
    float scv = SC[comm * 32768 + b * 512 + old];
    float sg = 1.f / (1.f + expf(-scv));

    float acc[4][8];
#pragma unroll
    for (int i = 0; i < 4; i++)
#pragma unroll
        for (int j = 0; j < 8; j++) acc[i][j] = 0.f;

    for (int k0 = 0; k0 < 384; k0 += 32) {
        __syncthreads();
#pragma unroll
        for (int qq = 0; qq < 2; qq++) {
            int kk = (aq + 4 * qq) * 4;
            float4 av = *(const float4*)(srow + k0 + kk);
            As[kk + 0][arow] = av.x * sg;
            As[kk + 1][arow] = av.y * sg;
            As[kk + 2][arow] = av.z * sg;
            As[kk + 3][arow] = av.w * sg;
        }
#pragma unroll
        for (int q = 0; q < 2; q++) {
            int f = tid + 512 * q;
            int kk = f >> 5, qd = f & 31;
            float4 wv = *(const float4*)(W + (size_t)k0 * 128 + f * 4);
            *(float4*)&Ws[kk * 128 + wswz(qd) * 4] = wv;
        }
        __syncthreads();
#pragma unroll 2
        for (int kk = 0; kk < 32; kk++) {
            int q0 = c0 >> 2;
            float4 a0 = *(const float4*)&As[kk][r0];
            float4 b0 = *(const float4*)&Ws[kk * 128 + wswz(q0) * 4];
            float4 b1 = *(const float4*)&Ws[kk * 128 + wswz(q0 + 1) * 4];
            float a[4] = {a0.x, a0.y, a0.z, a0.w};
            float b8[8] = {b0.x, b0.y, b0.z, b0.w, b1.x, b1.y, b1.z, b1.w};
#pragma unroll
            for (int i = 0; i < 4; i++)
#pragma unroll
                for (int j = 0; j < 8; j++)
                    acc[i][j] = fmaf(a[i], b8[j], acc[i][j]);
        }
    }
#pragma unroll
    for (int i = 0; i < 4; i++) {
        int row = row0 + r0 + i;
        float sc = rowscale[row];
        float4 o0 = {acc[i][0]*sc, acc[i][1]*sc, acc[i][2]*sc, acc[i][3]*sc};
        float4 o1 = {acc[i][4]*sc, acc[i][5]*sc, acc[i][6]*sc, acc[i][7]*sc};
        *(float4*)(C + (size_t)row * 128 + c0) = o0;
        *(float4*)(C + (size_t)row * 128 + c0 + 4) = o1;
    }
}

// ---------------- GCN aggregation (CSR gather, xw pre-scaled by dis[src]) ----------------
__global__ void k_aggregate4(const float* __restrict__ xwsc, const float* __restrict__ dis,
                             const int* __restrict__ rowstart, const int* __restrict__ csrc,
                             const float* __restrict__ bias, float* __restrict__ XC, int colbase) {
    int xcd  = blockIdx.x & 7;
    int slot = blockIdx.x >> 3;            // 0..1023
    int g    = ((slot >> 6) << 3) | xcd;   // 0..127
    int node = g * 512 + (slot & 63) * 8 + (threadIdx.x >> 5);
    int l    = threadIdx.x & 31;
    const float4* xw4 = (const float4*)xwsc;
    float4 acc = xw4[(size_t)node * 32 + l];
    int e0 = rowstart[node], e1 = rowstart[node + 1];
    for (int e = e0; e < e1; e++) {
        int s = csrc[e];
        float4 u = xw4[(size_t)s * 32 + l];
        acc.x += u.x; acc.y += u.y; acc.z += u.z; acc.w += u.w;
    }
    float di = dis[node];
    float4 b4 = ((const float4*)bias)[l];
    acc.x = fmaxf(acc.x * di + b4.x, 0.f);
    acc.y = fmaxf(acc.y * di + b4.y, 0.f);
    acc.z = fmaxf(acc.z * di + b4.z, 0.f);
    acc.w = fmaxf(acc.w * di + b4.w, 0.f);
    *(float4*)(XC + (size_t)node * 384 + colbase + l * 4) = acc;
}

// pooled variant: explicit count array (padded CSR regions)
__global__ void k_aggregate_pooled(const float* __restrict__ xwsc, const float* __restrict__ disp,
                                   const int* __restrict__ rowstart, const int* __restrict__ cntp,
                                   const int* __restrict__ csre,
                                   const float* __restrict__ bias, float* __restrict__ H) {
    int xcd  = blockIdx.x & 7;
    int slot = blockIdx.x >> 3;            // 0..511
    int g    = ((slot >> 5) << 3) | xcd;   // 0..127
    int node = g * 256 + (slot & 31) * 8 + (threadIdx.x >> 5);
    int l    = threadIdx.x & 31;
    const float4* xw4 = (const float4*)xwsc;
    float4 acc = xw4[(size_t)node * 32 + l];
    int e0 = rowstart[node], n = cntp[node];
    for (int i = 0; i < n; i++) {
        int r = csre[e0 + i];
        float4 u = xw4[(size_t)r * 32 + l];
        acc.x += u.x; acc.y += u.y; acc.z += u.z; acc.w += u.w;
    }
    float di = disp[node];
    float4 b4 = ((const float4*)bias)[l];
    acc.x = fmaxf(acc.x * di + b4.x, 0.f);
    acc.y = fmaxf(acc.y * di + b4.y, 0.f);
    acc.z = fmaxf(acc.z * di + b4.z, 0.f);
    acc.w = fmaxf(acc.w * di + b4.w, 0.f);
    *(float4*)(H + (size_t)node * 128 + l * 4) = acc;
}

// ---------------- attention pool stage 1 ----------------
__global__ void k_mean_part(const float* __restrict__ XC, float* __restrict__ mpart) {
    int blk = blockIdx.x;              // 0..511
    int gc = blk >> 2, p = blk & 3;
    int seg = ((gc & 1) << 6) | (gc >> 1);
    int c = threadIdx.x;               // 0..383
    int base = gc * 512 + p * 128;
    float s = 0.f;
    for (int i = 0; i < 128; i++) s += XC[(size_t)(base + i) * 384 + c];
    mpart[(size_t)(seg * 4 + p) * 384 + c] = s;
}

__global__ void k_c12(const float* __restrict__ mpart, const float* __restrict__ Wg,
                      float* __restrict__ c12) {
    __shared__ float ms[384];
    int seg = blockIdx.x; int c = threadIdx.x;   // 384 threads
    ms[c] = (mpart[(size_t)(seg * 4 + 0) * 384 + c] + mpart[(size_t)(seg * 4 + 1) * 384 + c] +
             mpart[(size_t)(seg * 4 + 2) * 384 + c] + mpart[(size_t)(seg * 4 + 3) * 384 + c]) *
            (1.0f / 512.0f);
    __syncthreads();
    float s = 0.f;
    for (int k = 0; k < 384; k++) s = fmaf(ms[k], Wg[(size_t)k * 384 + c], s);
    c12[seg * 384 + c] = tanhf(s);
}

__global__ __launch_bounds__(256) void k_attpool1(const float* __restrict__ XC,
                                                  const float* __restrict__ C12,
                                                  float* __restrict__ GP) {
    __shared__ float gps[4][384];
    int blk = blockIdx.x;              // 0..511 (4 per group)
    int gc = blk >> 2, q = blk & 3;
    int seg = ((gc & 1) << 6) | (gc >> 1);
    int w = threadIdx.x >> 6, l = threadIdx.x & 63;
    const float* c12r = C12 + seg * 384;
    float4 cr0 = *(const float4*)(c12r + 4 * l);
    float4 cr1 = (l < 32) ? *(const float4*)(c12r + 256 + 4 * l) : float4{0.f,0.f,0.f,0.f};
    float4 a0 = {0.f,0.f,0.f,0.f}, a1 = {0.f,0.f,0.f,0.f};
    int base = gc * 512 + q * 128 + w * 32;
    for (int it = 0; it < 32; it++) {
        const float* xr = XC + (size_t)(base + it) * 384;
        float4 v0 = *(const float4*)(xr + 4 * l);
        float4 v1 = (l < 32) ? *(const float4*)(xr + 256 + 4 * l) : float4{0.f,0.f,0.f,0.f};
        float s = v0.x*cr0.x + v0.y*cr0.y + v0.z*cr0.z + v0.w*cr0.w
                + v1.x*cr1.x + v1.y*cr1.y + v1.z*cr1.z + v1.w*cr1.w;
        for (int off = 32; off; off >>= 1) s += __shfl_xor(s, off);
        float al = 1.f / (1.f + expf(-s));
        a0.x += v0.x*al; a0.y += v0.y*al; a0.z += v0.z*al; a0.w += v0.w*al;
        a1.x += v1.x*al; a1.y += v1.y*al; a1.z += v1.z*al; a1.w += v1.w*al;
    }
    *(float4*)&gps[w][4 * l] = a0;
    if (l < 32) *(float4*)&gps[w][256 + 4 * l] = a1;
    __syncthreads();
    for (int c = threadIdx.x; c < 384; c += 256) {
        float s = gps[0][c] + gps[1][c] + gps[2][c] + gps[3][c];
        atomicAdd(&GP[seg * 384 + c], s);
    }
}

__global__ void k_pv(const float* __restrict__ gp, const float* __restrict__ Wal,
                     const float* __restrict__ bal, float* __restrict__ pv) {
    int row = blockIdx.x;               // 0..63
    int c   = threadIdx.x;              // 0..767
    float s = bal[c];
    for (int k = 0; k < 768; k++) {
        float v = (k < 384) ? gp[row * 384 + k] : gp[(64 + row) * 384 + (k - 384)];
        s = fmaf(v, Wal[(size_t)k * 768 + c], s);
    }
    pv[row * 768 + c] = s;
}

__global__ void k_pnorm(const float* __restrict__ pv, float* __restrict__ pnorm) {
    int id = blockIdx.x;                // 0..127 : comm = id>>6, b = id&63
    int lane = threadIdx.x;
    int h = id >> 6, b = id & 63;
    const float* p = pv + b * 768 + h * 384;
    float s = 0.f;
    for (int k = lane; k < 384; k += 64) s += p[k] * p[k];
    for (int off = 32; off; off >>= 1) s += __shfl_down(s, off);
    if (lane == 0) pnorm[id] = sqrtf(s);
}

// ---------------- scores (both communities) + per-batch top-K ----------------
__global__ void k_score(const float* __restrict__ XC, const float* __restrict__ pv,
                        const float* __restrict__ pnorm, float* __restrict__ sc) {
    int nl2 = blockIdx.x * 4 + (threadIdx.x >> 6);   // 0..65535
    int lane = threadIdx.x & 63;
    int comm = nl2 >> 15;
    int nl = nl2 & 32767;
    int b = nl >> 9; int i = nl & 511;
    const float* xr = XC + (size_t)(b * NPB + comm * 512 + i) * 384;
    const float* pr = pv + b * 768 + comm * 384;
    float4 x0 = *(const float4*)(xr + 4 * lane);
    float4 p0 = *(const float4*)(pr + 4 * lane);
    float s = x0.x*p0.x + x0.y*p0.y + x0.z*p0.z + x0.w*p0.w;
    if (lane < 32) {
        float4 x1 = *(const float4*)(xr + 256 + 4 * lane);
        float4 p1 = *(const float4*)(pr + 256 + 4 * lane);
        s += x1.x*p1.x + x1.y*p1.y + x1.z*p1.z + x1.w*p1.w;
    }
    for (int off = 32; off; off >>= 1) s += __shfl_down(s, off);
    if (lane == 0) sc[comm * 32768 + nl] = s / pnorm[comm * 64 + b];
}

__global__ void k_topk(const float* __restrict__ sc, int* __restrict__ sel, int* __restrict__ nmap) {
    __shared__ float sv[512];
    __shared__ int   si[512];
    int blk = blockIdx.x;               // 0..127 = comm*64 + b
    int t = threadIdx.x;                // 0..255
    sv[t] = sc[blk * 512 + t];             si[t] = t;
    sv[t + 256] = sc[blk * 512 + t + 256]; si[t + 256] = t + 256;
    __syncthreads();
    for (int k2 = 2; k2 <= 512; k2 <<= 1) {
        for (int j = k2 >> 1; j > 0; j >>= 1) {
            for (int i = t; i < 512; i += 256) {
                int l = i ^ j;
                if (l > i) {
                    bool desc = ((i & k2) == 0);
                    float a = sv[i], bb2 = sv[l];
                    bool sw = desc ? (a < bb2) : (a > bb2);
                    if (sw) {
                        sv[i] = bb2; sv[l] = a;
                        int tmp = si[i]; si[i] = si[l]; si[l] = tmp;
                    }
                }
            }
            __syncthreads();
        }
    }
    sel[blk * 256 + t] = si[t];                 // selected local idx (0..511)
    nmap[blk * 512 + si[t]] = blk * 256 + t;    // global pooled id
    nmap[blk * 512 + si[t + 256]] = -1;
}

// ---------------- final attention pools (2NP nodes, 128 segments of 256) ----------------
__global__ void k_meanf(const float* __restrict__ H, float* __restrict__ mean) {
    int b = blockIdx.x; int c = threadIdx.x;        // 128 blocks x 128 thr
    float s = 0.f;
    for (int i = 0; i < 256; i++) s += H[(size_t)(b * 256 + i) * 128 + c];
    mean[b * 128 + c] = s * (1.0f / 256.0f);
}

__global__ void k_cfin(const float* __restrict__ mean, const float* __restrict__ Wg,
                       float* __restrict__ cf) {
    __shared__ float ms[128];
    int b = blockIdx.x; int c = threadIdx.x;
    ms[c] = mean[b * 128 + c];
    __syncthreads();
    float s = 0.f;
    for (int k = 0; k < 128; k++) s = fmaf(ms[k], Wg[k * 128 + c], s);
    cf[b * 128 + c] = tanhf(s);
}

__global__ void k_alphaf(const float* __restrict__ H, const float* __restrict__ cf,
                         float* __restrict__ al) {
    int node = blockIdx.x * 4 + (threadIdx.x >> 6);
    int lane = threadIdx.x & 63;
    int b = node >> 8;
    float s = 0.f;
    if (lane < 32) {
        float4 h = *(const float4*)(H + (size_t)node * 128 + 4 * lane);
        float4 c = *(const float4*)(cf + b * 128 + 4 * lane);
        s = h.x*c.x + h.y*c.y + h.z*c.z + h.w*c.w;
    }
    for (int off = 32; off; off >>= 1) s += __shfl_down(s, off);
    if (lane == 0) al[node] = 1.f / (1.f + expf(-s));
}

__global__ void k_gfin(const float* __restrict__ H, const float* __restrict__ al,
                       float* __restrict__ g) {
    int seg = blockIdx.x; int c = threadIdx.x;      // 128 blocks x 128 thr
    int b = seg & 63, comm = seg >> 6;
    float s = 0.f;
    for (int i = 0; i < 256; i++) { int n = seg * 256 + i; s += H[(size_t)n * 128 + c] * al[n]; }
    g[b * 256 + comm * 128 + c] = s;
}

// ---------------- MLP head ----------------
__global__ void k_mlp(const float* __restrict__ G,
                      const float* __restrict__ Wl1, const float* __restrict__ bl1,
                      const float* __restrict__ Wl2, const float* __restrict__ bl2,
                      const float* __restrict__ Wl3, const float* __restrict__ bl3,
                      float* __restrict__ out) {
    __shared__ float t1[128], t2[64];
    int b = blockIdx.x; int t = threadIdx.x;        // 128 threads
    float s = bl1[t];
    for (int k = 0; k < 256; k++) s = fmaf(G[b * 256 + k], Wl1[k * 128 + t], s);
    t1[t] = fmaxf(s, 0.f);
    __syncthreads();
    if (t < 64) {
        float s2 = bl2[t];
        for (int k = 0; k < 128; k++) s2 = fmaf(t1[k], Wl2[k * 64 + t], s2);
        t2[t] = fmaxf(s2, 0.f);
    }
    __syncthreads();
    if (t < 2) {
        float s3 = bl3[t];
        for (int k = 0; k < 64; k++) s3 = fmaf(t2[k], Wl3[k * 2 + t], s3);
        out[b * 2 + t] = s3;
    }
}

// ---------------- launch ----------------
extern "C" void kernel_launch(void* const* d_in, const int* in_sizes, int n_in,
                              void* d_out, int out_size, void* d_ws, size_t ws_size,
                              hipStream_t stream) {
    const float* x       = (const float*)d_in[0];
    const int*   src_all = (const int*)d_in[1];
    const int*   dst_all = (const int*)d_in[2];
    const int*   src_c1  = (const int*)d_in[3];
    const int*   dst_c1  = (const int*)d_in[4];
    const int*   src_c2  = (const int*)d_in[5];
    const int*   dst_c2  = (const int*)d_in[6];
    const float* W1 = (const float*)d_in[7];   const float* b1 = (const float*)d_in[8];
    const float* W2 = (const float*)d_in[9];   const float* b2 = (const float*)d_in[10];
    const float* W3 = (const float*)d_in[11];  const float* b3 = (const float*)d_in[12];
    const float* Wg_att = (const float*)d_in[13];
    const float* Wal = (const float*)d_in[14]; const float* bal = (const float*)d_in[15];
    const float* Wf  = (const float*)d_in[16]; const float* bf  = (const float*)d_in[17];
    const float* Wg_fin = (const float*)d_in[18];
    const float* Wl1 = (const float*)d_in[19]; const float* bl1 = (const float*)d_in[20];
    const float* Wl2 = (const float*)d_in[21]; const float* bl2 = (const float*)d_in[22];
    const float* Wl3 = (const float*)d_in[23]; const float* bl3 = (const float*)d_in[24];
    float* out = (float*)d_out;

    // ---- workspace layout (floats) ----
    float* f = (float*)d_ws;
    size_t o = 0;
    float* XC   = f + o; o += (size_t)NN * 384;     // 96 MB
    float* SCR  = f + o; o += (size_t)NN * 128;     // 32 MB  xw*dis; later XWP (2NP x 128)
    float* H    = f + o; o += (size_t)NP2 * 128;    // 16 MB  pooled conv output
    int* ROWSTART = (int*)(f + o); o += 65552;      // full rowstart; later pooled rowstart
    int* CSRC     = (int*)(f + o); o += EALL;       // full CSR; later pooled padded CSR (1M)
    int* CNTP     = (int*)(f + o); o += NP2;        // pooled per-node edge counts
    float* DIS    = f + o; o += NN;
    float* MPART  = f + o; o += 512 * 384;
    float* C12    = f + o; o += 128 * 384;
    float* GP     = f + o; o += 128 * 384;
    float* PV     = f + o; o += 64 * 768;
    float* PNORM  = f + o; o += 128;
    float* SC     = f + o; o += 65536;
    int* SEL      = (int*)(f + o); o += NP2;
    int* NMAP     = (int*)(f + o); o += 65536;
    float* DISP   = f + o; o += NP2;
    float* MEANF  = f + o; o += 128 * 128;
    float* CFIN   = f + o; o += 128 * 128;
    float* ALF    = f + o; o += NP2;
    float* G12    = f + o; o += 64 * 256;
    size_t needed_bytes = o * sizeof(float);
    if (ws_size < needed_bytes) return;

    float* XWP = SCR;                   // pooled xw*sig*dis, 2NP x 128 (reuses SCR)

    // ---- full-graph CSR + degrees (single fused kernel, LDS counting sort) ----
    k_build_csr<<<128, 256, 0, stream>>>(src_all, dst_all, ROWSTART, CSRC, DIS);

    // ---- 3 GCN layers into XC columns (xw pre-scaled by dis[row]) ----
    k_gemm_tile<128><<<NN / 128, 256, 0, stream>>>(x, 128, W1, DIS, SCR, NN);
    k_aggregate4<<<NN / 8, 256, 0, stream>>>(SCR, DIS, ROWSTART, CSRC, b1, XC, 0);
    k_gemm_tile<128><<<NN / 128, 256, 0, stream>>>(XC + 0, 384, W2, DIS, SCR, NN);
    k_aggregate4<<<NN / 8, 256, 0, stream>>>(SCR, DIS, ROWSTART, CSRC, b2, XC, 128);
    k_gemm_tile<128><<<NN / 128, 256, 0, stream>>>(XC + 128, 384, W3, DIS, SCR, NN);
    k_aggregate4<<<NN / 8, 256, 0, stream>>>(SCR, DIS, ROWSTART, CSRC, b3, XC, 256);

    // ---- attention pool over communities ----
    k_mean_part<<<512, 384, 0, stream>>>(XC, MPART);
    k_c12<<<128, 384, 0, stream>>>(MPART, Wg_att, C12);
    hipMemsetAsync(GP, 0, 128 * 384 * sizeof(float), stream);
    k_attpool1<<<512, 256, 0, stream>>>(XC, C12, GP);
    k_pv<<<64, 768, 0, stream>>>(GP, Wal, bal, PV);
    k_pnorm<<<128, 64, 0, stream>>>(PV, PNORM);

    // ---- scores + top-K per (batch, community) ----
    k_score<<<65536 / 4, 256, 0, stream>>>(XC, PV, PNORM, SC);
    k_topk<<<128, 256, 0, stream>>>(SC, SEL, NMAP);

    // ---- pooled graph build (single fused kernel, LDS counting sort) ----
    k_build_csr_pooled<<<128, 256, 0, stream>>>(src_c1, dst_c1, src_c2, dst_c2,
                                                NMAP, ROWSTART, CNTP, CSRC, DISP);

    // ---- pooled GCN (gathered GEMM + CSR aggregate), both communities ----
    k_gemm_gather<<<NP2 / 128, 512, 0, stream>>>(XC, SEL, SC, DISP, Wf, XWP);
    k_aggregate_pooled<<<NP2 / 8, 256, 0, stream>>>(XWP, DISP, ROWSTART, CNTP, CSRC, bf, H);

    // ---- final attention pools (both communities in one pass) ----
    k_meanf<<<128, 128, 0, stream>>>(H, MEANF);
    k_cfin<<<128, 128, 0, stream>>>(MEANF, Wg_fin, CFIN);
    k_alphaf<<<NP2 / 4, 256, 0, stream>>>(H, CFIN, ALF);
    k_gfin<<<128, 128, 0, stream>>>(H, ALF, G12);

    // ---- MLP head ----
    k_mlp<<<64, 128, 0, stream>>>(G12, Wl1, bl1, Wl2, bl2, Wl3, bl3, out);
}